// Round 1
// baseline (3131.875 us; speedup 1.0000x reference)
//
#include <hip/hip_runtime.h>
#include <math.h>

#define NTOK   4096
#define DM     1024
#define NHEAD  16
#define HDIM   64
#define NEXP   8
#define CAP    1024
#define HID    2730
#define NFF2   5460

// ============================ pack weights ============================
// Wq[d][h*64+e] = q_w[h][d][e] ; Wlat[d][h*32+l]=ka_w[h][d][l], cols 512..: va_w
__global__ void pack_kernel(const float* __restrict__ q_w, const float* __restrict__ ka_w,
                            const float* __restrict__ va_w, float* __restrict__ Wq,
                            float* __restrict__ Wlat) {
  int idx = blockIdx.x * 256 + threadIdx.x;
  if (idx < 1048576) {
    int d = idx >> 10, nn = idx & 1023;
    int h = nn >> 6, e = nn & 63;
    Wq[idx] = q_w[((size_t)h * 1024 + d) * 64 + e];
  } else {
    int j = idx - 1048576;
    int d = j >> 10, nn = j & 1023;
    if (nn < 512) {
      int h = nn >> 5, l = nn & 31;
      Wlat[j] = ka_w[((size_t)h * 1024 + d) * 32 + l];
    } else {
      int c = nn - 512;
      int h = c >> 5, l = c & 31;
      Wlat[j] = va_w[((size_t)h * 1024 + d) * 32 + l];
    }
  }
}

// ============================ RMSNorm ============================
__global__ __launch_bounds__(256) void rms_kernel(const float* __restrict__ x,
                                                  const float* __restrict__ w,
                                                  float* __restrict__ out) {
  int row = blockIdx.x;
  int tid = threadIdx.x;
  const float4 v = ((const float4*)(x + (size_t)row * DM))[tid];
  float ss = v.x * v.x + v.y * v.y + v.z * v.z + v.w * v.w;
#pragma unroll
  for (int off = 32; off >= 1; off >>= 1) ss += __shfl_down(ss, off);
  __shared__ float red[4];
  if ((tid & 63) == 0) red[tid >> 6] = ss;
  __syncthreads();
  float tot = red[0] + red[1] + red[2] + red[3];
  float scale = rsqrtf(tot * (1.0f / 1024.0f) + 1e-5f);
  const float4 wv = ((const float4*)w)[tid];
  float4 o;
  o.x = v.x * scale * wv.x; o.y = v.y * scale * wv.y;
  o.z = v.z * scale * wv.z; o.w = v.w * scale * wv.w;
  ((float4*)(out + (size_t)row * DM))[tid] = o;
}

// ============================ generic 128x128 SGEMM ============================
// C[M,N] = A[M,K] @ B[K,N] (+bias[n]) (+res[m,n]). M,N mult of 128, K mult of 8.
template <bool BIAS, bool RES>
__global__ __launch_bounds__(256) void gemm128(const float* __restrict__ A,
                                               const float* __restrict__ Bm,
                                               const float* __restrict__ bias,
                                               const float* __restrict__ res,
                                               float* __restrict__ C, int K, int N) {
  __shared__ float As[8][128];
  __shared__ float Bs[8][128];
  int tid = threadIdx.x;
  int tx = tid & 15, ty = tid >> 4;
  int n0 = blockIdx.x * 128;
  int m0 = blockIdx.y * 128;
  float c[8][8] = {{0.f}};
  int arow = m0 + (tid >> 1);
  int ak = (tid & 1) * 4;
  int bk = tid >> 5;
  int bcol = n0 + (tid & 31) * 4;
  const float* Ap = A + (size_t)arow * K;
  for (int kc = 0; kc < K; kc += 8) {
    float4 av = *(const float4*)(Ap + kc + ak);
    As[ak + 0][tid >> 1] = av.x;
    As[ak + 1][tid >> 1] = av.y;
    As[ak + 2][tid >> 1] = av.z;
    As[ak + 3][tid >> 1] = av.w;
    float4 bv = *(const float4*)(Bm + (size_t)(kc + bk) * N + bcol);
    *(float4*)&Bs[bk][(tid & 31) * 4] = bv;
    __syncthreads();
#pragma unroll
    for (int kk = 0; kk < 8; kk++) {
      float a[8], b[8];
      *(float4*)&a[0] = *(const float4*)&As[kk][ty * 8];
      *(float4*)&a[4] = *(const float4*)&As[kk][ty * 8 + 4];
      *(float4*)&b[0] = *(const float4*)&Bs[kk][tx * 8];
      *(float4*)&b[4] = *(const float4*)&Bs[kk][tx * 8 + 4];
#pragma unroll
      for (int i = 0; i < 8; i++)
#pragma unroll
        for (int j = 0; j < 8; j++) c[i][j] += a[i] * b[j];
    }
    __syncthreads();
  }
#pragma unroll
  for (int i = 0; i < 8; i++) {
    int row = m0 + ty * 8 + i;
    float* cr = C + (size_t)row * N + n0 + tx * 8;
    const float* rr = res + (size_t)row * N + n0 + tx * 8;
#pragma unroll
    for (int j = 0; j < 8; j++) {
      float v = c[i][j];
      if (BIAS) v += bias[n0 + tx * 8 + j];
      if (RES) v += rr[j];
      cr[j] = v;
    }
  }
}

// ============================ latent -> K,V expand ============================
// kpre/vf layout (b,h,t,e). latents row bt: cols [h*32+l]=ka-latent, [512+h*32+l]=va-latent
__global__ void expand_kernel(const float* __restrict__ latents, const float* __restrict__ kb_w,
                              const float* __restrict__ vb_w, float* __restrict__ kpre,
                              float* __restrict__ vf) {
  int idx = blockIdx.x * 256 + threadIdx.x;  // 4M
  int e = idx & 63;
  int t = (idx >> 6) & 1023;
  int h = (idx >> 16) & 15;
  int b = idx >> 20;
  const float* lrow = latents + ((size_t)(b * 1024 + t)) * DM;
  const float* kb = kb_w + (size_t)h * 2048;
  const float* vb = vb_w + (size_t)h * 2048;
  float ka = 0.f, va = 0.f;
#pragma unroll
  for (int l = 0; l < 32; l++) {
    ka += lrow[h * 32 + l] * kb[l * 64 + e];
    va += lrow[512 + h * 32 + l] * vb[l * 64 + e];
  }
  kpre[idx] = ka;
  vf[idx] = va;
}

// ============================ RoPE ============================
// out layout (b,h,t,d). IN_BTHD=true: in is (bt, h*64+d) [q after gemm]; false: (b,h,t,d)
template <bool IN_BTHD>
__global__ void rope_kernel(const float* __restrict__ in, float* __restrict__ out) {
  int idx = blockIdx.x * 256 + threadIdx.x;  // 2M
  int i = idx & 31;
  int t = (idx >> 5) & 1023;
  int h = (idx >> 15) & 15;
  int b = idx >> 19;
  size_t ib;
  if (IN_BTHD)
    ib = ((size_t)(b * 1024 + t)) * DM + h * 64;
  else
    ib = ((size_t)((b * 16 + h) * 1024 + t)) * 64;
  float t1 = in[ib + 2 * i], t2 = in[ib + 2 * i + 1];
  float inv = exp2f(-(float)i * 0.41524101186091903f);  // 10000^(-i/32)
  float ang = (float)t * inv;
  float s, c;
  sincosf(ang, &s, &c);
  size_t ob = ((size_t)((b * 16 + h) * 1024 + t)) * 64;
  out[ob + i] = t1 * c - t2 * s;
  out[ob + 32 + i] = t1 * s + t2 * c;
}

// ============================ flash attention ============================
// per (b,h): full softmax over 1024 keys. o written as (bt, h*64+d).
__global__ __launch_bounds__(256) void attn_kernel(const float* __restrict__ qf,
                                                   const float* __restrict__ kf,
                                                   const float* __restrict__ vf,
                                                   float* __restrict__ o) {
  __shared__ float Qs[64][65];
  __shared__ float KPs[64][65];  // K tile, reused as P tile
  __shared__ float Vs[64][65];
  int bh = blockIdx.y;
  int q0 = blockIdx.x * 64;
  int tid = threadIdx.x;
  int tx = tid & 15, ty = tid >> 4;
  const size_t base = (size_t)bh * 1024 * 64;
#pragma unroll
  for (int it = 0; it < 4; it++) {
    int g = tid + it * 256;
    int r = g >> 4, d = (g & 15) * 4;
    float4 qv = *(const float4*)(qf + base + (size_t)(q0 + r) * 64 + d);
    Qs[r][d] = qv.x; Qs[r][d + 1] = qv.y; Qs[r][d + 2] = qv.z; Qs[r][d + 3] = qv.w;
  }
  float m[4], l[4], acc[4][4];
#pragma unroll
  for (int i = 0; i < 4; i++) {
    m[i] = -3.0e38f; l[i] = 0.f;
#pragma unroll
    for (int j = 0; j < 4; j++) acc[i][j] = 0.f;
  }
  for (int kt = 0; kt < 16; kt++) {
    __syncthreads();
#pragma unroll
    for (int it = 0; it < 4; it++) {
      int g = tid + it * 256;
      int r = g >> 4, d = (g & 15) * 4;
      float4 kv = *(const float4*)(kf + base + (size_t)(kt * 64 + r) * 64 + d);
      KPs[r][d] = kv.x; KPs[r][d + 1] = kv.y; KPs[r][d + 2] = kv.z; KPs[r][d + 3] = kv.w;
      float4 vv = *(const float4*)(vf + base + (size_t)(kt * 64 + r) * 64 + d);
      Vs[r][d] = vv.x; Vs[r][d + 1] = vv.y; Vs[r][d + 2] = vv.z; Vs[r][d + 3] = vv.w;
    }
    __syncthreads();
    float s[4][4] = {{0.f}};
    for (int d = 0; d < 64; d++) {
      float a0 = Qs[ty * 4 + 0][d], a1 = Qs[ty * 4 + 1][d], a2 = Qs[ty * 4 + 2][d], a3 = Qs[ty * 4 + 3][d];
      float b0 = KPs[tx * 4 + 0][d], b1 = KPs[tx * 4 + 1][d], b2 = KPs[tx * 4 + 2][d], b3 = KPs[tx * 4 + 3][d];
      s[0][0] += a0 * b0; s[0][1] += a0 * b1; s[0][2] += a0 * b2; s[0][3] += a0 * b3;
      s[1][0] += a1 * b0; s[1][1] += a1 * b1; s[1][2] += a1 * b2; s[1][3] += a1 * b3;
      s[2][0] += a2 * b0; s[2][1] += a2 * b1; s[2][2] += a2 * b2; s[2][3] += a2 * b3;
      s[3][0] += a3 * b0; s[3][1] += a3 * b1; s[3][2] += a3 * b2; s[3][3] += a3 * b3;
    }
    float p[4][4], alpha[4];
#pragma unroll
    for (int i = 0; i < 4; i++) {
#pragma unroll
      for (int j = 0; j < 4; j++) s[i][j] *= 0.125f;
      float rm = fmaxf(fmaxf(s[i][0], s[i][1]), fmaxf(s[i][2], s[i][3]));
      rm = fmaxf(rm, __shfl_xor(rm, 1));
      rm = fmaxf(rm, __shfl_xor(rm, 2));
      rm = fmaxf(rm, __shfl_xor(rm, 4));
      rm = fmaxf(rm, __shfl_xor(rm, 8));
      float newm = fmaxf(m[i], rm);
      alpha[i] = expf(m[i] - newm);
      float rs = 0.f;
#pragma unroll
      for (int j = 0; j < 4; j++) {
        p[i][j] = expf(s[i][j] - newm);
        rs += p[i][j];
      }
      rs += __shfl_xor(rs, 1);
      rs += __shfl_xor(rs, 2);
      rs += __shfl_xor(rs, 4);
      rs += __shfl_xor(rs, 8);
      l[i] = l[i] * alpha[i] + rs;
      m[i] = newm;
#pragma unroll
      for (int j = 0; j < 4; j++) acc[i][j] *= alpha[i];
    }
    __syncthreads();  // done reading K tile
#pragma unroll
    for (int i = 0; i < 4; i++)
#pragma unroll
      for (int j = 0; j < 4; j++) KPs[ty * 4 + i][tx * 4 + j] = p[i][j];
    __syncthreads();
    for (int ss = 0; ss < 64; ss++) {
      float p0 = KPs[ty * 4 + 0][ss], p1 = KPs[ty * 4 + 1][ss], p2 = KPs[ty * 4 + 2][ss], p3 = KPs[ty * 4 + 3][ss];
      float v0 = Vs[ss][tx * 4 + 0], v1 = Vs[ss][tx * 4 + 1], v2 = Vs[ss][tx * 4 + 2], v3 = Vs[ss][tx * 4 + 3];
      acc[0][0] += p0 * v0; acc[0][1] += p0 * v1; acc[0][2] += p0 * v2; acc[0][3] += p0 * v3;
      acc[1][0] += p1 * v0; acc[1][1] += p1 * v1; acc[1][2] += p1 * v2; acc[1][3] += p1 * v3;
      acc[2][0] += p2 * v0; acc[2][1] += p2 * v1; acc[2][2] += p2 * v2; acc[2][3] += p2 * v3;
      acc[3][0] += p3 * v0; acc[3][1] += p3 * v1; acc[3][2] += p3 * v2; acc[3][3] += p3 * v3;
    }
  }
  int b = bh >> 4, h = bh & 15;
#pragma unroll
  for (int i = 0; i < 4; i++) {
    float invl = 1.0f / l[i];
    float4 ov;
    ov.x = acc[i][0] * invl; ov.y = acc[i][1] * invl;
    ov.z = acc[i][2] * invl; ov.w = acc[i][3] * invl;
    *(float4*)(o + (size_t)(b * 1024 + q0 + ty * 4 + i) * DM + h * 64 + tx * 4) = ov;
  }
}

// ============================ router ============================
__global__ __launch_bounds__(256) void router_kernel(
    const float* __restrict__ xn2, const float* __restrict__ route_w,
    const float* __restrict__ route_b, const float* __restrict__ noise_w,
    const float* __restrict__ noise_b, const float* __restrict__ noise_eps,
    int* __restrict__ topi, float* __restrict__ flat_p, float* __restrict__ probsum,
    int* __restrict__ slotmap) {
  int wave = threadIdx.x >> 6;
  int lane = threadIdx.x & 63;
  int tk = blockIdx.x * 4 + wave;
  float acc[8] = {0.f}, nacc[8] = {0.f};
  const float* xr = xn2 + (size_t)tk * DM;
  for (int it = 0; it < 16; it++) {
    int d = it * 64 + lane;
    float xv = xr[d];
    const float* rw = route_w + d * 8;
    const float* nw = noise_w + d * 8;
#pragma unroll
    for (int e = 0; e < 8; e++) {
      acc[e] += xv * rw[e];
      nacc[e] += xv * nw[e];
    }
  }
#pragma unroll
  for (int off = 32; off >= 1; off >>= 1) {
#pragma unroll
    for (int e = 0; e < 8; e++) {
      acc[e] += __shfl_down(acc[e], off);
      nacc[e] += __shfl_down(nacc[e], off);
    }
  }
  if (lane == 0) {
    float noisy[8];
#pragma unroll
    for (int e = 0; e < 8; e++) {
      float lg = acc[e] + route_b[e];
      float nl = nacc[e] + noise_b[e];
      float sp = (nl > 20.f) ? nl : log1pf(expf(nl));
      noisy[e] = lg + noise_eps[tk * 8 + e] * sp;
    }
    int i1 = 0;
    float n1 = noisy[0];
#pragma unroll
    for (int e = 1; e < 8; e++)
      if (noisy[e] > n1) { n1 = noisy[e]; i1 = e; }
    int i2 = -1;
    float n2 = -3.0e38f;
#pragma unroll
    for (int e = 0; e < 8; e++)
      if (e != i1 && noisy[e] > n2) { n2 = noisy[e]; i2 = e; }
    float r = expf(n2 - n1);
    float p1 = 1.0f / (1.0f + r);
    float p2 = r / (1.0f + r);
    topi[tk * 2] = i1;
    topi[tk * 2 + 1] = i2;
#pragma unroll
    for (int e = 0; e < 8; e++) flat_p[tk * 8 + e] = (e == i1) ? p1 : ((e == i2) ? p2 : 0.f);
    atomicAdd(&probsum[i1], p1);
    atomicAdd(&probsum[i2], p2);
    slotmap[tk * 2] = -1;
    slotmap[tk * 2 + 1] = -1;
  }
}

// ============================ capacity scan ============================
// one block of 512: wave e compacts tokens selecting expert e, in token order, cap 1024
__global__ __launch_bounds__(512) void scan_kernel(const int* __restrict__ topi,
                                                   const float* __restrict__ flat_p,
                                                   int* __restrict__ tok, float* __restrict__ gate,
                                                   int* __restrict__ cnt, int* __restrict__ slotmap) {
  int e = threadIdx.x >> 6;
  int lane = threadIdx.x & 63;
  int count = 0;
  for (int base = 0; base < NTOK; base += 64) {
    int t = base + lane;
    int a = topi[t * 2], b = topi[t * 2 + 1];
    bool mflag = (a == e) || (b == e);
    unsigned long long mask = __ballot(mflag);
    int pos = count + __popcll(mask & ((1ull << lane) - 1ull));
    if (mflag && pos < CAP) {
      tok[e * CAP + pos] = t;
      gate[e * CAP + pos] = flat_p[t * 8 + e];
      int k = (a == e) ? 0 : 1;
      slotmap[t * 2 + k] = pos;
    }
    count += __popcll(mask);
  }
  if (lane == 0) cnt[e] = (count < CAP) ? count : CAP;
}

// ============================ expert GEMM 1: gathered x @ swiglu_w, fused SiLU ============================
// per block: 128 slots x 64 cols of BOTH halves; ACT[e][slot][j] = silu(h1)*h2
__global__ __launch_bounds__(256) void gemm_swiglu(const float* __restrict__ xn2,
                                                   const float* __restrict__ swiglu_w,
                                                   const int* __restrict__ tok,
                                                   const int* __restrict__ cnt,
                                                   float* __restrict__ ACT) {
  int e = blockIdx.z;
  int m0 = blockIdx.y * 128;
  int j0 = blockIdx.x * 64;
  __shared__ float As[8][128];
  __shared__ float B1s[8][64];
  __shared__ float B2s[8][64];
  __shared__ int tokL[128];
  int tid = threadIdx.x;
  if (tid < 128) {
    int slot = m0 + tid;
    tokL[tid] = (slot < cnt[e]) ? tok[e * CAP + slot] : -1;
  }
  __syncthreads();
  int tx = tid & 15, ty = tid >> 4;
  float c1[8][4] = {{0.f}}, c2[8][4] = {{0.f}};
  const float* Wb = swiglu_w + (size_t)e * DM * NFF2;
  int arow = tid >> 1;
  int ak = (tid & 1) * 4;
  int bk = tid >> 5;
  int bc = (tid & 31) * 2;
  bool bvalid = (j0 + bc) < HID;
  int srow = tokL[arow];
  for (int kc = 0; kc < DM; kc += 8) {
    float4 av = {0.f, 0.f, 0.f, 0.f};
    if (srow >= 0) av = *(const float4*)(xn2 + (size_t)srow * DM + kc + ak);
    As[ak + 0][arow] = av.x;
    As[ak + 1][arow] = av.y;
    As[ak + 2][arow] = av.z;
    As[ak + 3][arow] = av.w;
    float2 b1 = {0.f, 0.f}, b2 = {0.f, 0.f};
    if (bvalid) {
      const float* bp = Wb + (size_t)(kc + bk) * NFF2 + j0 + bc;
      b1 = *(const float2*)bp;
      b2 = *(const float2*)(bp + HID);
    }
    *(float2*)&B1s[bk][bc] = b1;
    *(float2*)&B2s[bk][bc] = b2;
    __syncthreads();
#pragma unroll
    for (int kk = 0; kk < 8; kk++) {
      float a[8];
      *(float4*)&a[0] = *(const float4*)&As[kk][ty * 8];
      *(float4*)&a[4] = *(const float4*)&As[kk][ty * 8 + 4];
      float b1r[4], b2r[4];
      *(float4*)&b1r[0] = *(const float4*)&B1s[kk][tx * 4];
      *(float4*)&b2r[0] = *(const float4*)&B2s[kk][tx * 4];
#pragma unroll
      for (int i = 0; i < 8; i++)
#pragma unroll
        for (int j = 0; j < 4; j++) {
          c1[i][j] += a[i] * b1r[j];
          c2[i][j] += a[i] * b2r[j];
        }
    }
    __syncthreads();
  }
#pragma unroll
  for (int j = 0; j < 4; j++) {
    int col = j0 + tx * 4 + j;
    if (col < HID) {
#pragma unroll
      for (int i = 0; i < 8; i++) {
        int row = m0 + ty * 8 + i;
        float h1 = c1[i][j], h2 = c2[i][j];
        float act = (h1 / (1.0f + expf(-h1))) * h2;
        ACT[(size_t)e * CAP * HID + (size_t)row * HID + col] = act;
      }
    }
  }
}

// ============================ expert GEMM 2: ACT @ down_w -> OE (K=2730 guarded) ============================
__global__ __launch_bounds__(256) void gemm_down(const float* __restrict__ ACT,
                                                 const float* __restrict__ down_w,
                                                 float* __restrict__ OE) {
  int e = blockIdx.z;
  int n0 = blockIdx.x * 128;
  int m0 = blockIdx.y * 128;
  const float* A = ACT + (size_t)e * CAP * HID;
  const float* Bm = down_w + (size_t)e * HID * DM;
  float* C = OE + ((size_t)e << 20);
  __shared__ float As[8][128];
  __shared__ float Bs[8][128];
  int tid = threadIdx.x;
  int tx = tid & 15, ty = tid >> 4;
  float c[8][8] = {{0.f}};
  int arow = m0 + (tid >> 1);
  int ak = (tid & 1) * 4;
  int bk = tid >> 5;
  int bcol = n0 + (tid & 31) * 4;
  const float* Ap = A + (size_t)arow * HID;
  for (int kc = 0; kc < HID; kc += 8) {
    float4 av;
    if (kc + ak + 3 < HID) {
      av = *(const float4*)(Ap + kc + ak);
    } else {
      av.x = (kc + ak + 0 < HID) ? Ap[kc + ak + 0] : 0.f;
      av.y = (kc + ak + 1 < HID) ? Ap[kc + ak + 1] : 0.f;
      av.z = (kc + ak + 2 < HID) ? Ap[kc + ak + 2] : 0.f;
      av.w = (kc + ak + 3 < HID) ? Ap[kc + ak + 3] : 0.f;
    }
    As[ak + 0][tid >> 1] = av.x;
    As[ak + 1][tid >> 1] = av.y;
    As[ak + 2][tid >> 1] = av.z;
    As[ak + 3][tid >> 1] = av.w;
    float4 bv = {0.f, 0.f, 0.f, 0.f};
    if (kc + bk < HID) bv = *(const float4*)(Bm + (size_t)(kc + bk) * DM + bcol);
    *(float4*)&Bs[bk][(tid & 31) * 4] = bv;
    __syncthreads();
#pragma unroll
    for (int kk = 0; kk < 8; kk++) {
      float a[8], b[8];
      *(float4*)&a[0] = *(const float4*)&As[kk][ty * 8];
      *(float4*)&a[4] = *(const float4*)&As[kk][ty * 8 + 4];
      *(float4*)&b[0] = *(const float4*)&Bs[kk][tx * 8];
      *(float4*)&b[4] = *(const float4*)&Bs[kk][tx * 8 + 4];
#pragma unroll
      for (int i = 0; i < 8; i++)
#pragma unroll
        for (int j = 0; j < 8; j++) c[i][j] += a[i] * b[j];
    }
    __syncthreads();
  }
#pragma unroll
  for (int i = 0; i < 8; i++) {
    float* cr = C + (size_t)(m0 + ty * 8 + i) * DM + n0 + tx * 8;
#pragma unroll
    for (int j = 0; j < 8; j++) cr[j] = c[i][j];
  }
}

// ============================ combine ============================
__global__ void combine_kernel(const float* __restrict__ x2, const float* __restrict__ OE,
                               const int* __restrict__ topi, const int* __restrict__ slotmap,
                               const float* __restrict__ flat_p, float* __restrict__ out) {
  int idx = blockIdx.x * 256 + threadIdx.x;  // 1M float4s
  int t = idx >> 8;
  int c4 = (idx & 255) * 4;
  float4 v = *(const float4*)(x2 + (size_t)t * DM + c4);
#pragma unroll
  for (int k = 0; k < 2; k++) {
    int s = slotmap[t * 2 + k];
    if (s >= 0) {
      int e = topi[t * 2 + k];
      float g = flat_p[t * 8 + e];
      float4 ov = *(const float4*)(OE + ((size_t)e << 20) + (size_t)s * DM + c4);
      v.x += g * ov.x; v.y += g * ov.y; v.z += g * ov.z; v.w += g * ov.w;
    }
  }
  *(float4*)(out + (size_t)t * DM + c4) = v;
}

__global__ void aux_kernel(const float* __restrict__ probsum, float* __restrict__ out) {
  if (threadIdx.x == 0) {
    float s = 0.f;
#pragma unroll
    for (int e = 0; e < 8; e++) {
      float d = probsum[e] * (1.0f / 4096.0f) - 0.125f;
      s += d * d;
    }
    out[4194304] = s;
  }
}

// ============================ launch ============================
extern "C" void kernel_launch(void* const* d_in, const int* in_sizes, int n_in, void* d_out,
                              int out_size, void* d_ws, size_t ws_size, hipStream_t stream) {
  const float* x = (const float*)d_in[0];
  const float* noise_eps = (const float*)d_in[1];
  const float* ln1_w = (const float*)d_in[2];
  const float* ln2_w = (const float*)d_in[3];
  const float* q_w = (const float*)d_in[4];
  const float* q_b = (const float*)d_in[5];
  const float* ka_w = (const float*)d_in[6];
  const float* kb_w = (const float*)d_in[7];
  const float* va_w = (const float*)d_in[8];
  const float* vb_w = (const float*)d_in[9];
  const float* proj_w = (const float*)d_in[10];
  const float* proj_b = (const float*)d_in[11];
  const float* route_w = (const float*)d_in[12];
  const float* route_b = (const float*)d_in[13];
  const float* noise_w = (const float*)d_in[14];
  const float* noise_b = (const float*)d_in[15];
  const float* swiglu_w = (const float*)d_in[16];
  const float* down_w = (const float*)d_in[17];
  float* out = (float*)d_out;
  char* w = (char*)d_ws;
  const size_t MB = 1ull << 20;
  float* xn = (float*)(w + 0 * MB);
  float* qtmp = (float*)(w + 16 * MB);
  float* latents = (float*)(w + 32 * MB);
  float* kpre = (float*)(w + 48 * MB);
  float* qfb = (float*)(w + 64 * MB);
  float* kfb = (float*)(w + 80 * MB);
  float* vfb = (float*)(w + 96 * MB);
  float* ob = (float*)(w + 112 * MB);
  float* ACT = (float*)(w + 0 * MB);    // 89.5 MB, aliases xn..kfb (dead by then)
  float* OE = (float*)(w + 96 * MB);    // 32 MB, aliases vfb+ob (dead by then)
  float* x2 = (float*)(w + 128 * MB);
  float* xn2 = (float*)(w + 144 * MB);
  float* Wq = (float*)(w + 160 * MB);
  float* Wlat = (float*)(w + 164 * MB);
  char* sm = w + 168 * MB;
  int* topi = (int*)sm;                       // 32 KB
  int* tok = (int*)(sm + 64 * 1024);          // 32 KB
  int* cntb = (int*)(sm + 128 * 1024);        // 32 B
  int* slotmap = (int*)(sm + 192 * 1024);     // 32 KB
  float* flat_p = (float*)(sm + 256 * 1024);  // 128 KB
  float* gateb = (float*)(sm + 512 * 1024);   // 32 KB
  float* probsum = (float*)(sm + 576 * 1024); // 32 B

  pack_kernel<<<8192, 256, 0, stream>>>(q_w, ka_w, va_w, Wq, Wlat);
  rms_kernel<<<4096, 256, 0, stream>>>(x, ln1_w, xn);
  gemm128<true, false><<<dim3(8, 32), 256, 0, stream>>>(xn, Wq, q_b, nullptr, qtmp, 1024, 1024);
  gemm128<false, false><<<dim3(8, 32), 256, 0, stream>>>(xn, Wlat, nullptr, nullptr, latents, 1024, 1024);
  expand_kernel<<<16384, 256, 0, stream>>>(latents, kb_w, vb_w, kpre, vfb);
  rope_kernel<true><<<8192, 256, 0, stream>>>(qtmp, qfb);
  rope_kernel<false><<<8192, 256, 0, stream>>>(kpre, kfb);
  attn_kernel<<<dim3(16, 64), 256, 0, stream>>>(qfb, kfb, vfb, ob);
  gemm128<true, true><<<dim3(8, 32), 256, 0, stream>>>(ob, proj_w, proj_b, x, x2, 1024, 1024);
  rms_kernel<<<4096, 256, 0, stream>>>(x2, ln2_w, xn2);
  hipMemsetAsync(probsum, 0, 8 * sizeof(float), stream);
  router_kernel<<<1024, 256, 0, stream>>>(xn2, route_w, route_b, noise_w, noise_b, noise_eps,
                                          topi, flat_p, probsum, slotmap);
  scan_kernel<<<1, 512, 0, stream>>>(topi, flat_p, tok, gateb, cntb, slotmap);
  gemm_swiglu<<<dim3(43, 8, 8), 256, 0, stream>>>(xn2, swiglu_w, tok, cntb, ACT);
  gemm_down<<<dim3(8, 8, 8), 256, 0, stream>>>(ACT, down_w, OE);
  combine_kernel<<<4096, 256, 0, stream>>>(x2, OE, topi, slotmap, flat_p, out);
  aux_kernel<<<1, 64, 0, stream>>>(probsum, out);
}

// Round 2
// 2031.509 us; speedup vs baseline: 1.5416x; 1.5416x over previous
//
#include <hip/hip_runtime.h>
#include <math.h>

#define NTOK   4096
#define DM     1024
#define NHEAD  16
#define HDIM   64
#define NEXP   8
#define CAP    1024
#define HID    2730
#define NFF2   5460
#define HIDP   2752   // HID padded to multiple of 32

typedef __attribute__((ext_vector_type(8))) short bf16x8;
typedef __attribute__((ext_vector_type(4))) float f32x4;

__device__ __forceinline__ unsigned short f2bf(float f) {
  unsigned int u = __float_as_uint(f);
  u += 0x7fffu + ((u >> 16) & 1u);
  return (unsigned short)(u >> 16);
}

// ============================ pack weights ============================
__global__ void pack_kernel(const float* __restrict__ q_w, const float* __restrict__ ka_w,
                            const float* __restrict__ va_w, float* __restrict__ Wq,
                            float* __restrict__ Wlat) {
  int idx = blockIdx.x * 256 + threadIdx.x;
  if (idx < 1048576) {
    int d = idx >> 10, nn = idx & 1023;
    int h = nn >> 6, e = nn & 63;
    Wq[idx] = q_w[((size_t)h * 1024 + d) * 64 + e];
  } else {
    int j = idx - 1048576;
    int d = j >> 10, nn = j & 1023;
    if (nn < 512) {
      int h = nn >> 5, l = nn & 31;
      Wlat[j] = ka_w[((size_t)h * 1024 + d) * 32 + l];
    } else {
      int c = nn - 512;
      int h = c >> 5, l = c & 31;
      Wlat[j] = va_w[((size_t)h * 1024 + d) * 32 + l];
    }
  }
}

// ============================ RMSNorm ============================
template <bool DUAL>
__global__ __launch_bounds__(256) void rms_kernel(const float* __restrict__ x,
                                                  const float* __restrict__ w,
                                                  float* __restrict__ out,
                                                  unsigned short* __restrict__ outb) {
  int row = blockIdx.x;
  int tid = threadIdx.x;
  const float4 v = ((const float4*)(x + (size_t)row * DM))[tid];
  float ss = v.x * v.x + v.y * v.y + v.z * v.z + v.w * v.w;
#pragma unroll
  for (int off = 32; off >= 1; off >>= 1) ss += __shfl_down(ss, off);
  __shared__ float red[4];
  if ((tid & 63) == 0) red[tid >> 6] = ss;
  __syncthreads();
  float tot = red[0] + red[1] + red[2] + red[3];
  float scale = rsqrtf(tot * (1.0f / 1024.0f) + 1e-5f);
  const float4 wv = ((const float4*)w)[tid];
  float4 o;
  o.x = v.x * scale * wv.x; o.y = v.y * scale * wv.y;
  o.z = v.z * scale * wv.z; o.w = v.w * scale * wv.w;
  ((float4*)(out + (size_t)row * DM))[tid] = o;
  if (DUAL) {
    ushort4 ob;
    ob.x = f2bf(o.x); ob.y = f2bf(o.y); ob.z = f2bf(o.z); ob.w = f2bf(o.w);
    *(ushort4*)(outb + (size_t)row * DM + tid * 4) = ob;
  }
}

// ============================ generic 128x128 SGEMM (dense path, fp32) ============================
template <bool BIAS, bool RES>
__global__ __launch_bounds__(256) void gemm128(const float* __restrict__ A,
                                               const float* __restrict__ Bm,
                                               const float* __restrict__ bias,
                                               const float* __restrict__ res,
                                               float* __restrict__ C, int K, int N) {
  __shared__ float As[8][128];
  __shared__ float Bs[8][128];
  int tid = threadIdx.x;
  int tx = tid & 15, ty = tid >> 4;
  int n0 = blockIdx.x * 128;
  int m0 = blockIdx.y * 128;
  float c[8][8] = {{0.f}};
  int arow = m0 + (tid >> 1);
  int ak = (tid & 1) * 4;
  int bk = tid >> 5;
  int bcol = n0 + (tid & 31) * 4;
  const float* Ap = A + (size_t)arow * K;
  for (int kc = 0; kc < K; kc += 8) {
    float4 av = *(const float4*)(Ap + kc + ak);
    As[ak + 0][tid >> 1] = av.x;
    As[ak + 1][tid >> 1] = av.y;
    As[ak + 2][tid >> 1] = av.z;
    As[ak + 3][tid >> 1] = av.w;
    float4 bv = *(const float4*)(Bm + (size_t)(kc + bk) * N + bcol);
    *(float4*)&Bs[bk][(tid & 31) * 4] = bv;
    __syncthreads();
#pragma unroll
    for (int kk = 0; kk < 8; kk++) {
      float a[8], b[8];
      *(float4*)&a[0] = *(const float4*)&As[kk][ty * 8];
      *(float4*)&a[4] = *(const float4*)&As[kk][ty * 8 + 4];
      *(float4*)&b[0] = *(const float4*)&Bs[kk][tx * 8];
      *(float4*)&b[4] = *(const float4*)&Bs[kk][tx * 8 + 4];
#pragma unroll
      for (int i = 0; i < 8; i++)
#pragma unroll
        for (int j = 0; j < 8; j++) c[i][j] += a[i] * b[j];
    }
    __syncthreads();
  }
#pragma unroll
  for (int i = 0; i < 8; i++) {
    int row = m0 + ty * 8 + i;
    float* cr = C + (size_t)row * N + n0 + tx * 8;
    const float* rr = res + (size_t)row * N + n0 + tx * 8;
#pragma unroll
    for (int j = 0; j < 8; j++) {
      float v = c[i][j];
      if (BIAS) v += bias[n0 + tx * 8 + j];
      if (RES) v += rr[j];
      cr[j] = v;
    }
  }
}

// ============================ latent -> K,V expand ============================
__global__ void expand_kernel(const float* __restrict__ latents, const float* __restrict__ kb_w,
                              const float* __restrict__ vb_w, float* __restrict__ kpre,
                              float* __restrict__ vf) {
  int idx = blockIdx.x * 256 + threadIdx.x;  // 4M
  int e = idx & 63;
  int t = (idx >> 6) & 1023;
  int h = (idx >> 16) & 15;
  int b = idx >> 20;
  const float* lrow = latents + ((size_t)(b * 1024 + t)) * DM;
  const float* kb = kb_w + (size_t)h * 2048;
  const float* vb = vb_w + (size_t)h * 2048;
  float ka = 0.f, va = 0.f;
#pragma unroll
  for (int l = 0; l < 32; l++) {
    ka += lrow[h * 32 + l] * kb[l * 64 + e];
    va += lrow[512 + h * 32 + l] * vb[l * 64 + e];
  }
  kpre[idx] = ka;
  vf[idx] = va;
}

// ============================ RoPE ============================
template <bool IN_BTHD>
__global__ void rope_kernel(const float* __restrict__ in, float* __restrict__ out) {
  int idx = blockIdx.x * 256 + threadIdx.x;  // 2M
  int i = idx & 31;
  int t = (idx >> 5) & 1023;
  int h = (idx >> 15) & 15;
  int b = idx >> 19;
  size_t ib;
  if (IN_BTHD)
    ib = ((size_t)(b * 1024 + t)) * DM + h * 64;
  else
    ib = ((size_t)((b * 16 + h) * 1024 + t)) * 64;
  float t1 = in[ib + 2 * i], t2 = in[ib + 2 * i + 1];
  float inv = exp2f(-(float)i * 0.41524101186091903f);  // 10000^(-i/32)
  float ang = (float)t * inv;
  float s, c;
  sincosf(ang, &s, &c);
  size_t ob = ((size_t)((b * 16 + h) * 1024 + t)) * 64;
  out[ob + i] = t1 * c - t2 * s;
  out[ob + 32 + i] = t1 * s + t2 * c;
}

// ============================ flash attention (fp32) ============================
__global__ __launch_bounds__(256) void attn_kernel(const float* __restrict__ qf,
                                                   const float* __restrict__ kf,
                                                   const float* __restrict__ vf,
                                                   float* __restrict__ o) {
  __shared__ float Qs[64][65];
  __shared__ float KPs[64][65];
  __shared__ float Vs[64][65];
  int bh = blockIdx.y;
  int q0 = blockIdx.x * 64;
  int tid = threadIdx.x;
  int tx = tid & 15, ty = tid >> 4;
  const size_t base = (size_t)bh * 1024 * 64;
#pragma unroll
  for (int it = 0; it < 4; it++) {
    int g = tid + it * 256;
    int r = g >> 4, d = (g & 15) * 4;
    float4 qv = *(const float4*)(qf + base + (size_t)(q0 + r) * 64 + d);
    Qs[r][d] = qv.x; Qs[r][d + 1] = qv.y; Qs[r][d + 2] = qv.z; Qs[r][d + 3] = qv.w;
  }
  float m[4], l[4], acc[4][4];
#pragma unroll
  for (int i = 0; i < 4; i++) {
    m[i] = -3.0e38f; l[i] = 0.f;
#pragma unroll
    for (int j = 0; j < 4; j++) acc[i][j] = 0.f;
  }
  for (int kt = 0; kt < 16; kt++) {
    __syncthreads();
#pragma unroll
    for (int it = 0; it < 4; it++) {
      int g = tid + it * 256;
      int r = g >> 4, d = (g & 15) * 4;
      float4 kv = *(const float4*)(kf + base + (size_t)(kt * 64 + r) * 64 + d);
      KPs[r][d] = kv.x; KPs[r][d + 1] = kv.y; KPs[r][d + 2] = kv.z; KPs[r][d + 3] = kv.w;
      float4 vv = *(const float4*)(vf + base + (size_t)(kt * 64 + r) * 64 + d);
      Vs[r][d] = vv.x; Vs[r][d + 1] = vv.y; Vs[r][d + 2] = vv.z; Vs[r][d + 3] = vv.w;
    }
    __syncthreads();
    float s[4][4] = {{0.f}};
    for (int d = 0; d < 64; d++) {
      float a0 = Qs[ty * 4 + 0][d], a1 = Qs[ty * 4 + 1][d], a2 = Qs[ty * 4 + 2][d], a3 = Qs[ty * 4 + 3][d];
      float b0 = KPs[tx * 4 + 0][d], b1 = KPs[tx * 4 + 1][d], b2 = KPs[tx * 4 + 2][d], b3 = KPs[tx * 4 + 3][d];
      s[0][0] += a0 * b0; s[0][1] += a0 * b1; s[0][2] += a0 * b2; s[0][3] += a0 * b3;
      s[1][0] += a1 * b0; s[1][1] += a1 * b1; s[1][2] += a1 * b2; s[1][3] += a1 * b3;
      s[2][0] += a2 * b0; s[2][1] += a2 * b1; s[2][2] += a2 * b2; s[2][3] += a2 * b3;
      s[3][0] += a3 * b0; s[3][1] += a3 * b1; s[3][2] += a3 * b2; s[3][3] += a3 * b3;
    }
    float p[4][4], alpha[4];
#pragma unroll
    for (int i = 0; i < 4; i++) {
#pragma unroll
      for (int j = 0; j < 4; j++) s[i][j] *= 0.125f;
      float rm = fmaxf(fmaxf(s[i][0], s[i][1]), fmaxf(s[i][2], s[i][3]));
      rm = fmaxf(rm, __shfl_xor(rm, 1));
      rm = fmaxf(rm, __shfl_xor(rm, 2));
      rm = fmaxf(rm, __shfl_xor(rm, 4));
      rm = fmaxf(rm, __shfl_xor(rm, 8));
      float newm = fmaxf(m[i], rm);
      alpha[i] = expf(m[i] - newm);
      float rs = 0.f;
#pragma unroll
      for (int j = 0; j < 4; j++) {
        p[i][j] = expf(s[i][j] - newm);
        rs += p[i][j];
      }
      rs += __shfl_xor(rs, 1);
      rs += __shfl_xor(rs, 2);
      rs += __shfl_xor(rs, 4);
      rs += __shfl_xor(rs, 8);
      l[i] = l[i] * alpha[i] + rs;
      m[i] = newm;
#pragma unroll
      for (int j = 0; j < 4; j++) acc[i][j] *= alpha[i];
    }
    __syncthreads();
#pragma unroll
    for (int i = 0; i < 4; i++)
#pragma unroll
      for (int j = 0; j < 4; j++) KPs[ty * 4 + i][tx * 4 + j] = p[i][j];
    __syncthreads();
    for (int ss = 0; ss < 64; ss++) {
      float p0 = KPs[ty * 4 + 0][ss], p1 = KPs[ty * 4 + 1][ss], p2 = KPs[ty * 4 + 2][ss], p3 = KPs[ty * 4 + 3][ss];
      float v0 = Vs[ss][tx * 4 + 0], v1 = Vs[ss][tx * 4 + 1], v2 = Vs[ss][tx * 4 + 2], v3 = Vs[ss][tx * 4 + 3];
      acc[0][0] += p0 * v0; acc[0][1] += p0 * v1; acc[0][2] += p0 * v2; acc[0][3] += p0 * v3;
      acc[1][0] += p1 * v0; acc[1][1] += p1 * v1; acc[1][2] += p1 * v2; acc[1][3] += p1 * v3;
      acc[2][0] += p2 * v0; acc[2][1] += p2 * v1; acc[2][2] += p2 * v2; acc[2][3] += p2 * v3;
      acc[3][0] += p3 * v0; acc[3][1] += p3 * v1; acc[3][2] += p3 * v2; acc[3][3] += p3 * v3;
    }
  }
  int b = bh >> 4, h = bh & 15;
#pragma unroll
  for (int i = 0; i < 4; i++) {
    float invl = 1.0f / l[i];
    float4 ov;
    ov.x = acc[i][0] * invl; ov.y = acc[i][1] * invl;
    ov.z = acc[i][2] * invl; ov.w = acc[i][3] * invl;
    *(float4*)(o + (size_t)(b * 1024 + q0 + ty * 4 + i) * DM + h * 64 + tx * 4) = ov;
  }
}

// ============================ router ============================
__global__ __launch_bounds__(256) void router_kernel(
    const float* __restrict__ xn2, const float* __restrict__ route_w,
    const float* __restrict__ route_b, const float* __restrict__ noise_w,
    const float* __restrict__ noise_b, const float* __restrict__ noise_eps,
    int* __restrict__ topi, float* __restrict__ flat_p, float* __restrict__ probsum,
    int* __restrict__ slotmap) {
  int wave = threadIdx.x >> 6;
  int lane = threadIdx.x & 63;
  int tk = blockIdx.x * 4 + wave;
  float acc[8] = {0.f}, nacc[8] = {0.f};
  const float* xr = xn2 + (size_t)tk * DM;
  for (int it = 0; it < 16; it++) {
    int d = it * 64 + lane;
    float xv = xr[d];
    const float* rw = route_w + d * 8;
    const float* nw = noise_w + d * 8;
#pragma unroll
    for (int e = 0; e < 8; e++) {
      acc[e] += xv * rw[e];
      nacc[e] += xv * nw[e];
    }
  }
#pragma unroll
  for (int off = 32; off >= 1; off >>= 1) {
#pragma unroll
    for (int e = 0; e < 8; e++) {
      acc[e] += __shfl_down(acc[e], off);
      nacc[e] += __shfl_down(nacc[e], off);
    }
  }
  if (lane == 0) {
    float noisy[8];
#pragma unroll
    for (int e = 0; e < 8; e++) {
      float lg = acc[e] + route_b[e];
      float nl = nacc[e] + noise_b[e];
      float sp = (nl > 20.f) ? nl : log1pf(expf(nl));
      noisy[e] = lg + noise_eps[tk * 8 + e] * sp;
    }
    int i1 = 0;
    float n1 = noisy[0];
#pragma unroll
    for (int e = 1; e < 8; e++)
      if (noisy[e] > n1) { n1 = noisy[e]; i1 = e; }
    int i2 = -1;
    float n2 = -3.0e38f;
#pragma unroll
    for (int e = 0; e < 8; e++)
      if (e != i1 && noisy[e] > n2) { n2 = noisy[e]; i2 = e; }
    float r = expf(n2 - n1);
    float p1 = 1.0f / (1.0f + r);
    float p2 = r / (1.0f + r);
    topi[tk * 2] = i1;
    topi[tk * 2 + 1] = i2;
#pragma unroll
    for (int e = 0; e < 8; e++) flat_p[tk * 8 + e] = (e == i1) ? p1 : ((e == i2) ? p2 : 0.f);
    atomicAdd(&probsum[i1], p1);
    atomicAdd(&probsum[i2], p2);
    slotmap[tk * 2] = -1;
    slotmap[tk * 2 + 1] = -1;
  }
}

// ============================ capacity scan ============================
__global__ __launch_bounds__(512) void scan_kernel(const int* __restrict__ topi,
                                                   const float* __restrict__ flat_p,
                                                   int* __restrict__ tok, float* __restrict__ gate,
                                                   int* __restrict__ cnt, int* __restrict__ slotmap) {
  int e = threadIdx.x >> 6;
  int lane = threadIdx.x & 63;
  int count = 0;
  for (int base = 0; base < NTOK; base += 64) {
    int t = base + lane;
    int a = topi[t * 2], b = topi[t * 2 + 1];
    bool mflag = (a == e) || (b == e);
    unsigned long long mask = __ballot(mflag);
    int pos = count + __popcll(mask & ((1ull << lane) - 1ull));
    if (mflag && pos < CAP) {
      tok[e * CAP + pos] = t;
      gate[e * CAP + pos] = flat_p[t * 8 + e];
      int k = (a == e) ? 0 : 1;
      slotmap[t * 2 + k] = pos;
    }
    count += __popcll(mask);
  }
  if (lane == 0) cnt[e] = (count < CAP) ? count : CAP;
}

// ============================ expert GEMM 1 (bf16 MFMA): gathered x @ swiglu_w, fused SiLU ======
// block: 128 slots x 64 output cols (both halves). ACT bf16 [e][slot][HIDP], pad cols zeroed.
__global__ __launch_bounds__(256) void mfma_swiglu(const unsigned short* __restrict__ xn2b,
                                                   const float* __restrict__ swiglu_w,
                                                   const int* __restrict__ tok,
                                                   const int* __restrict__ cnt,
                                                   unsigned short* __restrict__ ACT) {
  int e = blockIdx.z;
  int m0 = blockIdx.y * 128;
  int j0 = blockIdx.x * 64;
  __shared__ short As[128][40];   // stride 40 (80B, mult of 16B): 2-way bank alias = free
  __shared__ short B1s[64][40];
  __shared__ short B2s[64][40];
  __shared__ int tokL[128];
  int tid = threadIdx.x;
  if (tid < 128) {
    int slot = m0 + tid;
    tokL[tid] = (slot < cnt[e]) ? tok[e * CAP + slot] : -1;
  }
  __syncthreads();
  int wid = tid >> 6, lane = tid & 63;
  int wm0 = (wid >> 1) * 64, wn0 = (wid & 1) * 32;
  int lr = lane & 15, lq = lane >> 4;
  f32x4 c1[4][2], c2[4][2];
  f32x4 zz = {0.f, 0.f, 0.f, 0.f};
#pragma unroll
  for (int i = 0; i < 4; i++)
#pragma unroll
    for (int j = 0; j < 2; j++) { c1[i][j] = zz; c2[i][j] = zz; }
  const float* Wb = swiglu_w + (size_t)e * DM * NFF2;
  // per-thread staging coords
  int ar = tid >> 2;          // A rows (p*64 + ar)
  int aq = tid & 3;
  int tr0 = tokL[ar], tr1 = tokL[64 + ar];
  int bk0 = tid >> 4;         // B k (p*16 + bk0)
  int bn = (tid & 15) * 4;    // B n base
  int col = j0 + bn;          // output-col base for this thread's B loads

  for (int kc = 0; kc < DM; kc += 32) {
    __syncthreads();
    // ---- stage A (gathered, bf16 src) ----
    {
      float4 av = {0.f, 0.f, 0.f, 0.f};
      if (tr0 >= 0) av = *(const float4*)(xn2b + (size_t)tr0 * DM + kc + aq * 8);
      *(float4*)&As[ar][aq * 8] = av;
      float4 av2 = {0.f, 0.f, 0.f, 0.f};
      if (tr1 >= 0) av2 = *(const float4*)(xn2b + (size_t)tr1 * DM + kc + aq * 8);
      *(float4*)&As[64 + ar][aq * 8] = av2;
    }
    // ---- stage B halves (fp32 src, transpose+convert) ----
#pragma unroll
    for (int p = 0; p < 2; p++) {
      int k = p * 16 + bk0;
      const float* wp = Wb + (size_t)(kc + k) * NFF2 + col;
      float4 v1, v2;
      if (col + 3 < HID) {
        v1 = *(const float4*)wp;
        float2 lo = *(const float2*)(wp + HID);
        float2 hi = *(const float2*)(wp + HID + 2);
        v2.x = lo.x; v2.y = lo.y; v2.z = hi.x; v2.w = hi.y;
      } else {
        v1.x = (col + 0 < HID) ? wp[0] : 0.f;
        v1.y = (col + 1 < HID) ? wp[1] : 0.f;
        v1.z = (col + 2 < HID) ? wp[2] : 0.f;
        v1.w = (col + 3 < HID) ? wp[3] : 0.f;
        v2.x = (col + 0 < HID) ? wp[HID + 0] : 0.f;
        v2.y = (col + 1 < HID) ? wp[HID + 1] : 0.f;
        v2.z = (col + 2 < HID) ? wp[HID + 2] : 0.f;
        v2.w = (col + 3 < HID) ? wp[HID + 3] : 0.f;
      }
      B1s[bn + 0][k] = f2bf(v1.x); B1s[bn + 1][k] = f2bf(v1.y);
      B1s[bn + 2][k] = f2bf(v1.z); B1s[bn + 3][k] = f2bf(v1.w);
      B2s[bn + 0][k] = f2bf(v2.x); B2s[bn + 1][k] = f2bf(v2.y);
      B2s[bn + 2][k] = f2bf(v2.z); B2s[bn + 3][k] = f2bf(v2.w);
    }
    __syncthreads();
    // ---- fragments + MFMA ----
    bf16x8 a[4], b1[2], b2[2];
#pragma unroll
    for (int mi = 0; mi < 4; mi++) a[mi] = *(bf16x8*)&As[wm0 + mi * 16 + lr][lq * 8];
#pragma unroll
    for (int ni = 0; ni < 2; ni++) {
      b1[ni] = *(bf16x8*)&B1s[wn0 + ni * 16 + lr][lq * 8];
      b2[ni] = *(bf16x8*)&B2s[wn0 + ni * 16 + lr][lq * 8];
    }
#pragma unroll
    for (int mi = 0; mi < 4; mi++)
#pragma unroll
      for (int ni = 0; ni < 2; ni++) {
        c1[mi][ni] = __builtin_amdgcn_mfma_f32_16x16x32_bf16(a[mi], b1[ni], c1[mi][ni], 0, 0, 0);
        c2[mi][ni] = __builtin_amdgcn_mfma_f32_16x16x32_bf16(a[mi], b2[ni], c2[mi][ni], 0, 0, 0);
      }
  }
  // ---- epilogue: silu(h1)*h2 -> bf16 ACT ----
#pragma unroll
  for (int mi = 0; mi < 4; mi++)
#pragma unroll
    for (int ni = 0; ni < 2; ni++)
#pragma unroll
      for (int r = 0; r < 4; r++) {
        int mm = m0 + wm0 + mi * 16 + lq * 4 + r;
        int cc = j0 + wn0 + ni * 16 + lr;
        float h1 = c1[mi][ni][r], h2 = c2[mi][ni][r];
        float act = (h1 / (1.0f + expf(-h1))) * h2;
        ACT[(size_t)e * CAP * HIDP + (size_t)mm * HIDP + cc] = f2bf(act);
      }
}

// ============================ expert GEMM 2 (bf16 MFMA): ACT @ down_w -> OE fp32 ============
__global__ __launch_bounds__(256) void mfma_down(const unsigned short* __restrict__ ACT,
                                                 const float* __restrict__ down_w,
                                                 float* __restrict__ OE) {
  int e = blockIdx.z;
  int n0 = blockIdx.x * 128;
  int m0 = blockIdx.y * 128;
  __shared__ short As[128][40];
  __shared__ short Bs[128][40];
  int tid = threadIdx.x;
  int wid = tid >> 6, lane = tid & 63;
  int wm0 = (wid >> 1) * 64, wn0 = (wid & 1) * 64;
  int lr = lane & 15, lq = lane >> 4;
  f32x4 c[4][4];
  f32x4 zz = {0.f, 0.f, 0.f, 0.f};
#pragma unroll
  for (int i = 0; i < 4; i++)
#pragma unroll
    for (int j = 0; j < 4; j++) c[i][j] = zz;
  const unsigned short* Ab = ACT + (size_t)e * CAP * HIDP + (size_t)m0 * HIDP;
  const float* Bb = down_w + (size_t)e * HID * DM + n0;
  int ar = tid >> 2;
  int aq = tid & 3;
  int bk0 = tid >> 5;         // B k (p*8 + bk0)
  int bn = (tid & 31) * 4;

  for (int kc = 0; kc < HIDP; kc += 32) {
    __syncthreads();
    // ---- stage A (bf16, contiguous; pad cols are zeroed by mfma_swiglu) ----
    *(float4*)&As[ar][aq * 8] = *(const float4*)(Ab + (size_t)ar * HIDP + kc + aq * 8);
    *(float4*)&As[64 + ar][aq * 8] = *(const float4*)(Ab + (size_t)(64 + ar) * HIDP + kc + aq * 8);
    // ---- stage B (fp32 src, transpose+convert, K-guard) ----
#pragma unroll
    for (int p = 0; p < 4; p++) {
      int k = p * 8 + bk0;
      int kk = kc + k;
      float4 v = {0.f, 0.f, 0.f, 0.f};
      if (kk < HID) v = *(const float4*)(Bb + (size_t)kk * DM + bn);
      Bs[bn + 0][k] = f2bf(v.x); Bs[bn + 1][k] = f2bf(v.y);
      Bs[bn + 2][k] = f2bf(v.z); Bs[bn + 3][k] = f2bf(v.w);
    }
    __syncthreads();
    bf16x8 a[4], b[4];
#pragma unroll
    for (int mi = 0; mi < 4; mi++) a[mi] = *(bf16x8*)&As[wm0 + mi * 16 + lr][lq * 8];
#pragma unroll
    for (int ni = 0; ni < 4; ni++) b[ni] = *(bf16x8*)&Bs[wn0 + ni * 16 + lr][lq * 8];
#pragma unroll
    for (int mi = 0; mi < 4; mi++)
#pragma unroll
      for (int ni = 0; ni < 4; ni++)
        c[mi][ni] = __builtin_amdgcn_mfma_f32_16x16x32_bf16(a[mi], b[ni], c[mi][ni], 0, 0, 0);
  }
#pragma unroll
  for (int mi = 0; mi < 4; mi++)
#pragma unroll
    for (int ni = 0; ni < 4; ni++)
#pragma unroll
      for (int r = 0; r < 4; r++) {
        int mm = m0 + wm0 + mi * 16 + lq * 4 + r;
        int nn = n0 + wn0 + ni * 16 + lr;
        OE[((size_t)e << 20) + (size_t)mm * DM + nn] = c[mi][ni][r];
      }
}

// ============================ combine ============================
__global__ void combine_kernel(const float* __restrict__ x2, const float* __restrict__ OE,
                               const int* __restrict__ topi, const int* __restrict__ slotmap,
                               const float* __restrict__ flat_p, float* __restrict__ out) {
  int idx = blockIdx.x * 256 + threadIdx.x;  // 1M float4s
  int t = idx >> 8;
  int c4 = (idx & 255) * 4;
  float4 v = *(const float4*)(x2 + (size_t)t * DM + c4);
#pragma unroll
  for (int k = 0; k < 2; k++) {
    int s = slotmap[t * 2 + k];
    if (s >= 0) {
      int e = topi[t * 2 + k];
      float g = flat_p[t * 8 + e];
      float4 ov = *(const float4*)(OE + ((size_t)e << 20) + (size_t)s * DM + c4);
      v.x += g * ov.x; v.y += g * ov.y; v.z += g * ov.z; v.w += g * ov.w;
    }
  }
  *(float4*)(out + (size_t)t * DM + c4) = v;
}

__global__ void aux_kernel(const float* __restrict__ probsum, float* __restrict__ out) {
  if (threadIdx.x == 0) {
    float s = 0.f;
#pragma unroll
    for (int e = 0; e < 8; e++) {
      float d = probsum[e] * (1.0f / 4096.0f) - 0.125f;
      s += d * d;
    }
    out[4194304] = s;
  }
}

// ============================ launch ============================
extern "C" void kernel_launch(void* const* d_in, const int* in_sizes, int n_in, void* d_out,
                              int out_size, void* d_ws, size_t ws_size, hipStream_t stream) {
  const float* x = (const float*)d_in[0];
  const float* noise_eps = (const float*)d_in[1];
  const float* ln1_w = (const float*)d_in[2];
  const float* ln2_w = (const float*)d_in[3];
  const float* q_w = (const float*)d_in[4];
  const float* q_b = (const float*)d_in[5];
  const float* ka_w = (const float*)d_in[6];
  const float* kb_w = (const float*)d_in[7];
  const float* va_w = (const float*)d_in[8];
  const float* vb_w = (const float*)d_in[9];
  const float* proj_w = (const float*)d_in[10];
  const float* proj_b = (const float*)d_in[11];
  const float* route_w = (const float*)d_in[12];
  const float* route_b = (const float*)d_in[13];
  const float* noise_w = (const float*)d_in[14];
  const float* noise_b = (const float*)d_in[15];
  const float* swiglu_w = (const float*)d_in[16];
  const float* down_w = (const float*)d_in[17];
  float* out = (float*)d_out;
  char* w = (char*)d_ws;
  const size_t MB = 1ull << 20;
  float* xn = (float*)(w + 0 * MB);
  float* qtmp = (float*)(w + 16 * MB);
  float* latents = (float*)(w + 32 * MB);
  float* kpre = (float*)(w + 48 * MB);
  float* qfb = (float*)(w + 64 * MB);
  float* kfb = (float*)(w + 80 * MB);
  float* vfb = (float*)(w + 96 * MB);
  float* ob = (float*)(w + 112 * MB);
  // expert phase aliases (dense temps dead by then):
  unsigned short* ACT = (unsigned short*)(w + 0 * MB);  // bf16, 8*1024*2752*2 = 43 MB
  float* OE = (float*)(w + 48 * MB);                    // fp32, 32 MB (48..80)
  float* x2 = (float*)(w + 128 * MB);
  float* xn2 = (float*)(w + 144 * MB);
  float* Wq = (float*)(w + 160 * MB);
  float* Wlat = (float*)(w + 164 * MB);
  unsigned short* xn2b = (unsigned short*)(w + 160 * MB);  // bf16 8 MB, after Wq/Wlat dead
  char* sm = w + 168 * MB;
  int* topi = (int*)sm;
  int* tok = (int*)(sm + 64 * 1024);
  int* cntb = (int*)(sm + 128 * 1024);
  int* slotmap = (int*)(sm + 192 * 1024);
  float* flat_p = (float*)(sm + 256 * 1024);
  float* gateb = (float*)(sm + 512 * 1024);
  float* probsum = (float*)(sm + 576 * 1024);

  pack_kernel<<<8192, 256, 0, stream>>>(q_w, ka_w, va_w, Wq, Wlat);
  rms_kernel<false><<<4096, 256, 0, stream>>>(x, ln1_w, xn, nullptr);
  gemm128<true, false><<<dim3(8, 32), 256, 0, stream>>>(xn, Wq, q_b, nullptr, qtmp, 1024, 1024);
  gemm128<false, false><<<dim3(8, 32), 256, 0, stream>>>(xn, Wlat, nullptr, nullptr, latents, 1024, 1024);
  expand_kernel<<<16384, 256, 0, stream>>>(latents, kb_w, vb_w, kpre, vfb);
  rope_kernel<true><<<8192, 256, 0, stream>>>(qtmp, qfb);
  rope_kernel<false><<<8192, 256, 0, stream>>>(kpre, kfb);
  attn_kernel<<<dim3(16, 64), 256, 0, stream>>>(qfb, kfb, vfb, ob);
  gemm128<true, true><<<dim3(8, 32), 256, 0, stream>>>(ob, proj_w, proj_b, x, x2, 1024, 1024);
  rms_kernel<true><<<4096, 256, 0, stream>>>(x2, ln2_w, xn2, xn2b);
  hipMemsetAsync(probsum, 0, 8 * sizeof(float), stream);
  router_kernel<<<1024, 256, 0, stream>>>(xn2, route_w, route_b, noise_w, noise_b, noise_eps,
                                          topi, flat_p, probsum, slotmap);
  scan_kernel<<<1, 512, 0, stream>>>(topi, flat_p, tok, gateb, cntb, slotmap);
  mfma_swiglu<<<dim3(43, 8, 8), 256, 0, stream>>>(xn2b, swiglu_w, tok, cntb, ACT);
  mfma_down<<<dim3(8, 8, 8), 256, 0, stream>>>(ACT, down_w, OE);
  combine_kernel<<<4096, 256, 0, stream>>>(x2, OE, topi, slotmap, flat_p, out);
  aux_kernel<<<1, 64, 0, stream>>>(probsum, out);
}

// Round 3
// 1377.748 us; speedup vs baseline: 2.2732x; 1.4745x over previous
//
#include <hip/hip_runtime.h>
#include <math.h>

#define NTOK   4096
#define DM     1024
#define NHEAD  16
#define HDIM   64
#define NEXP   8
#define CAP    1024
#define HID    2730
#define NFF2   5460
#define HIDP   2752   // HID padded to multiple of 32

typedef __attribute__((ext_vector_type(8))) short bf16x8;
typedef __attribute__((ext_vector_type(4))) float f32x4;
typedef __attribute__((ext_vector_type(8))) _Float16 h16x8;
typedef __attribute__((ext_vector_type(4))) _Float16 h16x4;
typedef __attribute__((ext_vector_type(8))) unsigned short u16x8;

__device__ __forceinline__ unsigned short f2bf(float f) {
  unsigned int u = __float_as_uint(f);
  u += 0x7fffu + ((u >> 16) & 1u);
  return (unsigned short)(u >> 16);
}

// ============================ pack weights ============================
__global__ void pack_kernel(const float* __restrict__ q_w, const float* __restrict__ ka_w,
                            const float* __restrict__ va_w, float* __restrict__ Wq,
                            float* __restrict__ Wlat) {
  int idx = blockIdx.x * 256 + threadIdx.x;
  if (idx < 1048576) {
    int d = idx >> 10, nn = idx & 1023;
    int h = nn >> 6, e = nn & 63;
    Wq[idx] = q_w[((size_t)h * 1024 + d) * 64 + e];
  } else {
    int j = idx - 1048576;
    int d = j >> 10, nn = j & 1023;
    if (nn < 512) {
      int h = nn >> 5, l = nn & 31;
      Wlat[j] = ka_w[((size_t)h * 1024 + d) * 32 + l];
    } else {
      int c = nn - 512;
      int h = c >> 5, l = c & 31;
      Wlat[j] = va_w[((size_t)h * 1024 + d) * 32 + l];
    }
  }
}

// ============================ RMSNorm ============================
template <bool DUAL>
__global__ __launch_bounds__(256) void rms_kernel(const float* __restrict__ x,
                                                  const float* __restrict__ w,
                                                  float* __restrict__ out,
                                                  unsigned short* __restrict__ outb) {
  int row = blockIdx.x;
  int tid = threadIdx.x;
  const float4 v = ((const float4*)(x + (size_t)row * DM))[tid];
  float ss = v.x * v.x + v.y * v.y + v.z * v.z + v.w * v.w;
#pragma unroll
  for (int off = 32; off >= 1; off >>= 1) ss += __shfl_down(ss, off);
  __shared__ float red[4];
  if ((tid & 63) == 0) red[tid >> 6] = ss;
  __syncthreads();
  float tot = red[0] + red[1] + red[2] + red[3];
  float scale = rsqrtf(tot * (1.0f / 1024.0f) + 1e-5f);
  const float4 wv = ((const float4*)w)[tid];
  float4 o;
  o.x = v.x * scale * wv.x; o.y = v.y * scale * wv.y;
  o.z = v.z * scale * wv.z; o.w = v.w * scale * wv.w;
  ((float4*)(out + (size_t)row * DM))[tid] = o;
  if (DUAL) {
    ushort4 ob;
    ob.x = f2bf(o.x); ob.y = f2bf(o.y); ob.z = f2bf(o.z); ob.w = f2bf(o.w);
    *(ushort4*)(outb + (size_t)row * DM + tid * 4) = ob;
  }
}

// ============================ dense bf16 MFMA GEMM ============================
// C[M,N] = A[M,K]@B[K,N] (+bias)(+res). A,B fp32 (converted in staging). K,N mult of 32/128.
template <bool BIAS, bool RES>
__global__ __launch_bounds__(256) void mfma_dense(const float* __restrict__ A,
                                                  const float* __restrict__ Bm,
                                                  const float* __restrict__ bias,
                                                  const float* __restrict__ res,
                                                  float* __restrict__ C, int K, int N) {
  int n0 = blockIdx.x * 128;
  int m0 = blockIdx.y * 128;
  __shared__ short As[128][40];
  __shared__ short Bs[128][40];
  int tid = threadIdx.x;
  int wid = tid >> 6, lane = tid & 63;
  int wm0 = (wid >> 1) * 64, wn0 = (wid & 1) * 64;
  int lr = lane & 15, lq = lane >> 4;
  f32x4 c[4][4];
  f32x4 zz = {0.f, 0.f, 0.f, 0.f};
#pragma unroll
  for (int i = 0; i < 4; i++)
#pragma unroll
    for (int j = 0; j < 4; j++) c[i][j] = zz;
  int ar = tid >> 2;
  int aq = tid & 3;
  int bk0 = tid >> 5;
  int bn = (tid & 31) * 4;
  for (int kc = 0; kc < K; kc += 32) {
    __syncthreads();
#pragma unroll
    for (int rr = 0; rr < 2; rr++) {
      int row = rr * 64 + ar;
      const float* ap = A + (size_t)(m0 + row) * K + kc + aq * 8;
      float4 a0 = *(const float4*)ap;
      float4 a1 = *(const float4*)(ap + 4);
      u16x8 pk;
      pk[0] = f2bf(a0.x); pk[1] = f2bf(a0.y); pk[2] = f2bf(a0.z); pk[3] = f2bf(a0.w);
      pk[4] = f2bf(a1.x); pk[5] = f2bf(a1.y); pk[6] = f2bf(a1.z); pk[7] = f2bf(a1.w);
      *(u16x8*)&As[row][aq * 8] = pk;
    }
#pragma unroll
    for (int p = 0; p < 4; p++) {
      int k = p * 8 + bk0;
      float4 v = *(const float4*)(Bm + (size_t)(kc + k) * N + n0 + bn);
      Bs[bn + 0][k] = f2bf(v.x); Bs[bn + 1][k] = f2bf(v.y);
      Bs[bn + 2][k] = f2bf(v.z); Bs[bn + 3][k] = f2bf(v.w);
    }
    __syncthreads();
    bf16x8 a[4], b[4];
#pragma unroll
    for (int mi = 0; mi < 4; mi++) a[mi] = *(bf16x8*)&As[wm0 + mi * 16 + lr][lq * 8];
#pragma unroll
    for (int ni = 0; ni < 4; ni++) b[ni] = *(bf16x8*)&Bs[wn0 + ni * 16 + lr][lq * 8];
#pragma unroll
    for (int mi = 0; mi < 4; mi++)
#pragma unroll
      for (int ni = 0; ni < 4; ni++)
        c[mi][ni] = __builtin_amdgcn_mfma_f32_16x16x32_bf16(a[mi], b[ni], c[mi][ni], 0, 0, 0);
  }
#pragma unroll
  for (int mi = 0; mi < 4; mi++)
#pragma unroll
    for (int ni = 0; ni < 4; ni++) {
      int nn = n0 + wn0 + ni * 16 + lr;
      float bv = BIAS ? bias[nn] : 0.f;
#pragma unroll
      for (int r = 0; r < 4; r++) {
        int mm = m0 + wm0 + mi * 16 + lq * 4 + r;
        float v = c[mi][ni][r] + bv;
        if (RES) v += res[(size_t)mm * N + nn];
        C[(size_t)mm * N + nn] = v;
      }
    }
}

// ============================ latent -> K,V expand (V out f16) ============================
__global__ void expand_kernel(const float* __restrict__ latents, const float* __restrict__ kb_w,
                              const float* __restrict__ vb_w, float* __restrict__ kpre,
                              _Float16* __restrict__ vf) {
  int idx = blockIdx.x * 256 + threadIdx.x;  // 4M
  int e = idx & 63;
  int t = (idx >> 6) & 1023;
  int h = (idx >> 16) & 15;
  int b = idx >> 20;
  const float* lrow = latents + ((size_t)(b * 1024 + t)) * DM;
  const float* kb = kb_w + (size_t)h * 2048;
  const float* vb = vb_w + (size_t)h * 2048;
  float ka = 0.f, va = 0.f;
#pragma unroll
  for (int l = 0; l < 32; l++) {
    ka += lrow[h * 32 + l] * kb[l * 64 + e];
    va += lrow[512 + h * 32 + l] * vb[l * 64 + e];
  }
  kpre[idx] = ka;
  vf[idx] = (_Float16)va;
}

// ============================ RoPE (out f16) ============================
template <bool IN_BTHD>
__global__ void rope_kernel(const float* __restrict__ in, _Float16* __restrict__ out) {
  int idx = blockIdx.x * 256 + threadIdx.x;  // 2M
  int i = idx & 31;
  int t = (idx >> 5) & 1023;
  int h = (idx >> 15) & 15;
  int b = idx >> 19;
  size_t ib;
  if (IN_BTHD)
    ib = ((size_t)(b * 1024 + t)) * DM + h * 64;
  else
    ib = ((size_t)((b * 16 + h) * 1024 + t)) * 64;
  float t1 = in[ib + 2 * i], t2 = in[ib + 2 * i + 1];
  float inv = exp2f(-(float)i * 0.41524101186091903f);  // 10000^(-i/32)
  float ang = (float)t * inv;
  float s, c;
  sincosf(ang, &s, &c);
  size_t ob = ((size_t)((b * 16 + h) * 1024 + t)) * 64;
  out[ob + i] = (_Float16)(t1 * c - t2 * s);
  out[ob + 32 + i] = (_Float16)(t1 * s + t2 * c);
}

// ============================ flash attention (f16 MFMA) ============================
// grid (16 qtiles, 64 bh), 256 thr. Computes S^T = K@Q^T so P feeds PV directly from regs.
__global__ __launch_bounds__(256) void attn_mfma(const _Float16* __restrict__ qf,
                                                 const _Float16* __restrict__ kf,
                                                 const _Float16* __restrict__ vf,
                                                 float* __restrict__ o) {
  __shared__ _Float16 Ks[64][72];  // [key][dim], 144B rows = 9x16B (odd)
  __shared__ _Float16 Vt[64][68];  // [dim][key], 136B rows = 17x8B (odd)
  int bh = blockIdx.y;
  int q0 = blockIdx.x * 64;
  int tid = threadIdx.x;
  int wv = tid >> 6, lane = tid & 63;
  int lr = lane & 15, lq = lane >> 4;
  const size_t base = (size_t)bh * 1024 * 64;
  // Q fragments in registers: query = q0 + wv*16 + lr, k-chunk kc: dims kc*32 + lq*8 + j
  const _Float16* qrow = qf + base + (size_t)(q0 + wv * 16 + lr) * 64;
  h16x8 qfr[2];
  qfr[0] = *(const h16x8*)(qrow + lq * 8);
  qfr[1] = *(const h16x8*)(qrow + 32 + lq * 8);
  float mrow = -3.0e38f, lsum = 0.f;
  f32x4 oacc[4];  // O^T: dim = dt*16 + lq*4 + r, query = lane&15
  f32x4 zz = {0.f, 0.f, 0.f, 0.f};
#pragma unroll
  for (int i = 0; i < 4; i++) oacc[i] = zz;
  // staging coords
  int skey = tid >> 2, spart = tid & 3;      // K: key, dim-quarter
  int vkey = tid & 63, vdb = (tid >> 6) * 16;  // V: key, dim-base

  for (int kt = 0; kt < 16; kt++) {
    __syncthreads();
    {
      const _Float16* kg = kf + base + (size_t)(kt * 64 + skey) * 64 + spart * 16;
      *(h16x8*)&Ks[skey][spart * 16] = *(const h16x8*)kg;
      *(h16x8*)&Ks[skey][spart * 16 + 8] = *(const h16x8*)(kg + 8);
      const _Float16* vg = vf + base + (size_t)(kt * 64 + vkey) * 64 + vdb;
      h16x8 v0 = *(const h16x8*)vg;
      h16x8 v1 = *(const h16x8*)(vg + 8);
#pragma unroll
      for (int j = 0; j < 8; j++) {
        Vt[vdb + j][vkey] = v0[j];
        Vt[vdb + 8 + j][vkey] = v1[j];
      }
    }
    __syncthreads();
    // S^T: st[ni][r] = score[key = ni*16 + lq*4 + r][query = lane&15]
    f32x4 st[4];
#pragma unroll
    for (int ni = 0; ni < 4; ni++) {
      st[ni] = zz;
#pragma unroll
      for (int kc = 0; kc < 2; kc++) {
        h16x8 ak = *(const h16x8*)&Ks[ni * 16 + lr][kc * 32 + lq * 8];
        st[ni] = __builtin_amdgcn_mfma_f32_16x16x32_f16(ak, qfr[kc], st[ni], 0, 0, 0);
      }
    }
    // softmax over the 64 keys of this tile (per query = per lane, reduce over regs + lq)
    float smax = -3.0e38f;
#pragma unroll
    for (int ni = 0; ni < 4; ni++)
#pragma unroll
      for (int r = 0; r < 4; r++) {
        st[ni][r] *= 0.125f;
        smax = fmaxf(smax, st[ni][r]);
      }
    smax = fmaxf(smax, __shfl_xor(smax, 16));
    smax = fmaxf(smax, __shfl_xor(smax, 32));
    float newm = fmaxf(mrow, smax);
    float alpha = expf(mrow - newm);
    float rsum = 0.f;
    h16x4 pf[4];
#pragma unroll
    for (int ni = 0; ni < 4; ni++)
#pragma unroll
      for (int r = 0; r < 4; r++) {
        float p = expf(st[ni][r] - newm);
        rsum += p;
        pf[ni][r] = (_Float16)p;
      }
    rsum += __shfl_xor(rsum, 16);
    rsum += __shfl_xor(rsum, 32);
    lsum = lsum * alpha + rsum;
    mrow = newm;
#pragma unroll
    for (int dt = 0; dt < 4; dt++) {
      oacc[dt][0] *= alpha; oacc[dt][1] *= alpha;
      oacc[dt][2] *= alpha; oacc[dt][3] *= alpha;
    }
    // PV: O^T[dim][query] += V^T[dim][key] * P[query][key]
#pragma unroll
    for (int dt = 0; dt < 4; dt++)
#pragma unroll
      for (int ni = 0; ni < 4; ni++) {
        h16x4 va = *(const h16x4*)&Vt[dt * 16 + lr][ni * 16 + lq * 4];
        oacc[dt] = __builtin_amdgcn_mfma_f32_16x16x16f16(va, pf[ni], oacc[dt], 0, 0, 0);
      }
  }
  // epilogue: query = lane&15 per lane; dims dt*16 + lq*4 + r
  int b = bh >> 4, h = bh & 15;
  int qg = q0 + wv * 16 + lr;
  float invl = 1.0f / lsum;
  float* orow = o + (size_t)(b * 1024 + qg) * DM + h * 64;
#pragma unroll
  for (int dt = 0; dt < 4; dt++)
#pragma unroll
    for (int r = 0; r < 4; r++) orow[dt * 16 + lq * 4 + r] = oacc[dt][r] * invl;
}

// ============================ router ============================
__global__ __launch_bounds__(256) void router_kernel(
    const float* __restrict__ xn2, const float* __restrict__ route_w,
    const float* __restrict__ route_b, const float* __restrict__ noise_w,
    const float* __restrict__ noise_b, const float* __restrict__ noise_eps,
    int* __restrict__ topi, float* __restrict__ flat_p, float* __restrict__ probsum,
    int* __restrict__ slotmap) {
  int wave = threadIdx.x >> 6;
  int lane = threadIdx.x & 63;
  int tk = blockIdx.x * 4 + wave;
  float acc[8] = {0.f}, nacc[8] = {0.f};
  const float* xr = xn2 + (size_t)tk * DM;
  for (int it = 0; it < 16; it++) {
    int d = it * 64 + lane;
    float xv = xr[d];
    const float* rw = route_w + d * 8;
    const float* nw = noise_w + d * 8;
#pragma unroll
    for (int e = 0; e < 8; e++) {
      acc[e] += xv * rw[e];
      nacc[e] += xv * nw[e];
    }
  }
#pragma unroll
  for (int off = 32; off >= 1; off >>= 1) {
#pragma unroll
    for (int e = 0; e < 8; e++) {
      acc[e] += __shfl_down(acc[e], off);
      nacc[e] += __shfl_down(nacc[e], off);
    }
  }
  if (lane == 0) {
    float noisy[8];
#pragma unroll
    for (int e = 0; e < 8; e++) {
      float lg = acc[e] + route_b[e];
      float nl = nacc[e] + noise_b[e];
      float sp = (nl > 20.f) ? nl : log1pf(expf(nl));
      noisy[e] = lg + noise_eps[tk * 8 + e] * sp;
    }
    int i1 = 0;
    float n1 = noisy[0];
#pragma unroll
    for (int e = 1; e < 8; e++)
      if (noisy[e] > n1) { n1 = noisy[e]; i1 = e; }
    int i2 = -1;
    float n2 = -3.0e38f;
#pragma unroll
    for (int e = 0; e < 8; e++)
      if (e != i1 && noisy[e] > n2) { n2 = noisy[e]; i2 = e; }
    float r = expf(n2 - n1);
    float p1 = 1.0f / (1.0f + r);
    float p2 = r / (1.0f + r);
    topi[tk * 2] = i1;
    topi[tk * 2 + 1] = i2;
#pragma unroll
    for (int e = 0; e < 8; e++) flat_p[tk * 8 + e] = (e == i1) ? p1 : ((e == i2) ? p2 : 0.f);
    atomicAdd(&probsum[i1], p1);
    atomicAdd(&probsum[i2], p2);
    slotmap[tk * 2] = -1;
    slotmap[tk * 2 + 1] = -1;
  }
}

// ============================ capacity scan ============================
__global__ __launch_bounds__(512) void scan_kernel(const int* __restrict__ topi,
                                                   const float* __restrict__ flat_p,
                                                   int* __restrict__ tok, float* __restrict__ gate,
                                                   int* __restrict__ cnt, int* __restrict__ slotmap) {
  int e = threadIdx.x >> 6;
  int lane = threadIdx.x & 63;
  int count = 0;
  for (int base = 0; base < NTOK; base += 64) {
    int t = base + lane;
    int a = topi[t * 2], b = topi[t * 2 + 1];
    bool mflag = (a == e) || (b == e);
    unsigned long long mask = __ballot(mflag);
    int pos = count + __popcll(mask & ((1ull << lane) - 1ull));
    if (mflag && pos < CAP) {
      tok[e * CAP + pos] = t;
      gate[e * CAP + pos] = flat_p[t * 8 + e];
      int k = (a == e) ? 0 : 1;
      slotmap[t * 2 + k] = pos;
    }
    count += __popcll(mask);
  }
  if (lane == 0) cnt[e] = (count < CAP) ? count : CAP;
}

// ============================ expert GEMM 1 (bf16 MFMA): gathered x @ swiglu_w, fused SiLU ======
__global__ __launch_bounds__(256) void mfma_swiglu(const unsigned short* __restrict__ xn2b,
                                                   const float* __restrict__ swiglu_w,
                                                   const int* __restrict__ tok,
                                                   const int* __restrict__ cnt,
                                                   unsigned short* __restrict__ ACT) {
  int e = blockIdx.z;
  int m0 = blockIdx.y * 128;
  int j0 = blockIdx.x * 64;
  __shared__ short As[128][40];
  __shared__ short B1s[64][40];
  __shared__ short B2s[64][40];
  __shared__ int tokL[128];
  int tid = threadIdx.x;
  if (tid < 128) {
    int slot = m0 + tid;
    tokL[tid] = (slot < cnt[e]) ? tok[e * CAP + slot] : -1;
  }
  __syncthreads();
  int wid = tid >> 6, lane = tid & 63;
  int wm0 = (wid >> 1) * 64, wn0 = (wid & 1) * 32;
  int lr = lane & 15, lq = lane >> 4;
  f32x4 c1[4][2], c2[4][2];
  f32x4 zz = {0.f, 0.f, 0.f, 0.f};
#pragma unroll
  for (int i = 0; i < 4; i++)
#pragma unroll
    for (int j = 0; j < 2; j++) { c1[i][j] = zz; c2[i][j] = zz; }
  const float* Wb = swiglu_w + (size_t)e * DM * NFF2;
  int ar = tid >> 2;
  int aq = tid & 3;
  int tr0 = tokL[ar], tr1 = tokL[64 + ar];
  int bk0 = tid >> 4;
  int bn = (tid & 15) * 4;
  int col = j0 + bn;

  for (int kc = 0; kc < DM; kc += 32) {
    __syncthreads();
    {
      float4 av = {0.f, 0.f, 0.f, 0.f};
      if (tr0 >= 0) av = *(const float4*)(xn2b + (size_t)tr0 * DM + kc + aq * 8);
      *(float4*)&As[ar][aq * 8] = av;
      float4 av2 = {0.f, 0.f, 0.f, 0.f};
      if (tr1 >= 0) av2 = *(const float4*)(xn2b + (size_t)tr1 * DM + kc + aq * 8);
      *(float4*)&As[64 + ar][aq * 8] = av2;
    }
#pragma unroll
    for (int p = 0; p < 2; p++) {
      int k = p * 16 + bk0;
      const float* wp = Wb + (size_t)(kc + k) * NFF2 + col;
      float4 v1, v2;
      if (col + 3 < HID) {
        v1 = *(const float4*)wp;
        float2 lo = *(const float2*)(wp + HID);
        float2 hi = *(const float2*)(wp + HID + 2);
        v2.x = lo.x; v2.y = lo.y; v2.z = hi.x; v2.w = hi.y;
      } else {
        v1.x = (col + 0 < HID) ? wp[0] : 0.f;
        v1.y = (col + 1 < HID) ? wp[1] : 0.f;
        v1.z = (col + 2 < HID) ? wp[2] : 0.f;
        v1.w = (col + 3 < HID) ? wp[3] : 0.f;
        v2.x = (col + 0 < HID) ? wp[HID + 0] : 0.f;
        v2.y = (col + 1 < HID) ? wp[HID + 1] : 0.f;
        v2.z = (col + 2 < HID) ? wp[HID + 2] : 0.f;
        v2.w = (col + 3 < HID) ? wp[HID + 3] : 0.f;
      }
      B1s[bn + 0][k] = f2bf(v1.x); B1s[bn + 1][k] = f2bf(v1.y);
      B1s[bn + 2][k] = f2bf(v1.z); B1s[bn + 3][k] = f2bf(v1.w);
      B2s[bn + 0][k] = f2bf(v2.x); B2s[bn + 1][k] = f2bf(v2.y);
      B2s[bn + 2][k] = f2bf(v2.z); B2s[bn + 3][k] = f2bf(v2.w);
    }
    __syncthreads();
    bf16x8 a[4], b1[2], b2[2];
#pragma unroll
    for (int mi = 0; mi < 4; mi++) a[mi] = *(bf16x8*)&As[wm0 + mi * 16 + lr][lq * 8];
#pragma unroll
    for (int ni = 0; ni < 2; ni++) {
      b1[ni] = *(bf16x8*)&B1s[wn0 + ni * 16 + lr][lq * 8];
      b2[ni] = *(bf16x8*)&B2s[wn0 + ni * 16 + lr][lq * 8];
    }
#pragma unroll
    for (int mi = 0; mi < 4; mi++)
#pragma unroll
      for (int ni = 0; ni < 2; ni++) {
        c1[mi][ni] = __builtin_amdgcn_mfma_f32_16x16x32_bf16(a[mi], b1[ni], c1[mi][ni], 0, 0, 0);
        c2[mi][ni] = __builtin_amdgcn_mfma_f32_16x16x32_bf16(a[mi], b2[ni], c2[mi][ni], 0, 0, 0);
      }
  }
#pragma unroll
  for (int mi = 0; mi < 4; mi++)
#pragma unroll
    for (int ni = 0; ni < 2; ni++)
#pragma unroll
      for (int r = 0; r < 4; r++) {
        int mm = m0 + wm0 + mi * 16 + lq * 4 + r;
        int cc = j0 + wn0 + ni * 16 + lr;
        float h1 = c1[mi][ni][r], h2 = c2[mi][ni][r];
        float act = (h1 / (1.0f + expf(-h1))) * h2;
        ACT[(size_t)e * CAP * HIDP + (size_t)mm * HIDP + cc] = f2bf(act);
      }
}

// ============================ expert GEMM 2 (bf16 MFMA): ACT @ down_w -> OE fp32 ============
__global__ __launch_bounds__(256) void mfma_down(const unsigned short* __restrict__ ACT,
                                                 const float* __restrict__ down_w,
                                                 float* __restrict__ OE) {
  int e = blockIdx.z;
  int n0 = blockIdx.x * 128;
  int m0 = blockIdx.y * 128;
  __shared__ short As[128][40];
  __shared__ short Bs[128][40];
  int tid = threadIdx.x;
  int wid = tid >> 6, lane = tid & 63;
  int wm0 = (wid >> 1) * 64, wn0 = (wid & 1) * 64;
  int lr = lane & 15, lq = lane >> 4;
  f32x4 c[4][4];
  f32x4 zz = {0.f, 0.f, 0.f, 0.f};
#pragma unroll
  for (int i = 0; i < 4; i++)
#pragma unroll
    for (int j = 0; j < 4; j++) c[i][j] = zz;
  const unsigned short* Ab = ACT + (size_t)e * CAP * HIDP + (size_t)m0 * HIDP;
  const float* Bb = down_w + (size_t)e * HID * DM + n0;
  int ar = tid >> 2;
  int aq = tid & 3;
  int bk0 = tid >> 5;
  int bn = (tid & 31) * 4;

  for (int kc = 0; kc < HIDP; kc += 32) {
    __syncthreads();
    *(float4*)&As[ar][aq * 8] = *(const float4*)(Ab + (size_t)ar * HIDP + kc + aq * 8);
    *(float4*)&As[64 + ar][aq * 8] = *(const float4*)(Ab + (size_t)(64 + ar) * HIDP + kc + aq * 8);
#pragma unroll
    for (int p = 0; p < 4; p++) {
      int k = p * 8 + bk0;
      int kk = kc + k;
      float4 v = {0.f, 0.f, 0.f, 0.f};
      if (kk < HID) v = *(const float4*)(Bb + (size_t)kk * DM + bn);
      Bs[bn + 0][k] = f2bf(v.x); Bs[bn + 1][k] = f2bf(v.y);
      Bs[bn + 2][k] = f2bf(v.z); Bs[bn + 3][k] = f2bf(v.w);
    }
    __syncthreads();
    bf16x8 a[4], b[4];
#pragma unroll
    for (int mi = 0; mi < 4; mi++) a[mi] = *(bf16x8*)&As[wm0 + mi * 16 + lr][lq * 8];
#pragma unroll
    for (int ni = 0; ni < 4; ni++) b[ni] = *(bf16x8*)&Bs[wn0 + ni * 16 + lr][lq * 8];
#pragma unroll
    for (int mi = 0; mi < 4; mi++)
#pragma unroll
      for (int ni = 0; ni < 4; ni++)
        c[mi][ni] = __builtin_amdgcn_mfma_f32_16x16x32_bf16(a[mi], b[ni], c[mi][ni], 0, 0, 0);
  }
#pragma unroll
  for (int mi = 0; mi < 4; mi++)
#pragma unroll
    for (int ni = 0; ni < 4; ni++)
#pragma unroll
      for (int r = 0; r < 4; r++) {
        int mm = m0 + wm0 + mi * 16 + lq * 4 + r;
        int nn = n0 + wn0 + ni * 16 + lr;
        OE[((size_t)e << 20) + (size_t)mm * DM + nn] = c[mi][ni][r];
      }
}

// ============================ combine ============================
__global__ void combine_kernel(const float* __restrict__ x2, const float* __restrict__ OE,
                               const int* __restrict__ topi, const int* __restrict__ slotmap,
                               const float* __restrict__ flat_p, float* __restrict__ out) {
  int idx = blockIdx.x * 256 + threadIdx.x;  // 1M float4s
  int t = idx >> 8;
  int c4 = (idx & 255) * 4;
  float4 v = *(const float4*)(x2 + (size_t)t * DM + c4);
#pragma unroll
  for (int k = 0; k < 2; k++) {
    int s = slotmap[t * 2 + k];
    if (s >= 0) {
      int e = topi[t * 2 + k];
      float g = flat_p[t * 8 + e];
      float4 ov = *(const float4*)(OE + ((size_t)e << 20) + (size_t)s * DM + c4);
      v.x += g * ov.x; v.y += g * ov.y; v.z += g * ov.z; v.w += g * ov.w;
    }
  }
  *(float4*)(out + (size_t)t * DM + c4) = v;
}

__global__ void aux_kernel(const float* __restrict__ probsum, float* __restrict__ out) {
  if (threadIdx.x == 0) {
    float s = 0.f;
#pragma unroll
    for (int e = 0; e < 8; e++) {
      float d = probsum[e] * (1.0f / 4096.0f) - 0.125f;
      s += d * d;
    }
    out[4194304] = s;
  }
}

// ============================ launch ============================
extern "C" void kernel_launch(void* const* d_in, const int* in_sizes, int n_in, void* d_out,
                              int out_size, void* d_ws, size_t ws_size, hipStream_t stream) {
  const float* x = (const float*)d_in[0];
  const float* noise_eps = (const float*)d_in[1];
  const float* ln1_w = (const float*)d_in[2];
  const float* ln2_w = (const float*)d_in[3];
  const float* q_w = (const float*)d_in[4];
  const float* q_b = (const float*)d_in[5];
  const float* ka_w = (const float*)d_in[6];
  const float* kb_w = (const float*)d_in[7];
  const float* va_w = (const float*)d_in[8];
  const float* vb_w = (const float*)d_in[9];
  const float* proj_w = (const float*)d_in[10];
  const float* proj_b = (const float*)d_in[11];
  const float* route_w = (const float*)d_in[12];
  const float* route_b = (const float*)d_in[13];
  const float* noise_w = (const float*)d_in[14];
  const float* noise_b = (const float*)d_in[15];
  const float* swiglu_w = (const float*)d_in[16];
  const float* down_w = (const float*)d_in[17];
  float* out = (float*)d_out;
  char* w = (char*)d_ws;
  const size_t MB = 1ull << 20;
  float* xn = (float*)(w + 0 * MB);
  float* qtmp = (float*)(w + 16 * MB);
  float* latents = (float*)(w + 32 * MB);
  float* kpre = (float*)(w + 48 * MB);
  _Float16* qfb = (_Float16*)(w + 64 * MB);   // 8 MB
  _Float16* kfb = (_Float16*)(w + 72 * MB);   // 8 MB
  _Float16* vfb = (_Float16*)(w + 80 * MB);   // 8 MB
  float* ob = (float*)(w + 88 * MB);          // 16 MB -> ends 104
  unsigned short* ACT = (unsigned short*)(w + 0 * MB);  // bf16 43 MB (xn/qtmp/latents dead)
  float* OE = (float*)(w + 48 * MB);                    // 32 MB (kpre/qkv-f16 dead)
  float* x2 = (float*)(w + 128 * MB);
  float* xn2 = (float*)(w + 144 * MB);
  float* Wq = (float*)(w + 160 * MB);
  float* Wlat = (float*)(w + 164 * MB);
  unsigned short* xn2b = (unsigned short*)(w + 160 * MB);  // bf16 8 MB, after Wq/Wlat dead
  char* sm = w + 168 * MB;
  int* topi = (int*)sm;
  int* tok = (int*)(sm + 64 * 1024);
  int* cntb = (int*)(sm + 128 * 1024);
  int* slotmap = (int*)(sm + 192 * 1024);
  float* flat_p = (float*)(sm + 256 * 1024);
  float* gateb = (float*)(sm + 512 * 1024);
  float* probsum = (float*)(sm + 576 * 1024);

  pack_kernel<<<8192, 256, 0, stream>>>(q_w, ka_w, va_w, Wq, Wlat);
  rms_kernel<false><<<4096, 256, 0, stream>>>(x, ln1_w, xn, nullptr);
  mfma_dense<true, false><<<dim3(8, 32), 256, 0, stream>>>(xn, Wq, q_b, nullptr, qtmp, 1024, 1024);
  mfma_dense<false, false><<<dim3(8, 32), 256, 0, stream>>>(xn, Wlat, nullptr, nullptr, latents, 1024, 1024);
  expand_kernel<<<16384, 256, 0, stream>>>(latents, kb_w, vb_w, kpre, vfb);
  rope_kernel<true><<<8192, 256, 0, stream>>>(qtmp, qfb);
  rope_kernel<false><<<8192, 256, 0, stream>>>(kpre, kfb);
  attn_mfma<<<dim3(16, 64), 256, 0, stream>>>(qfb, kfb, vfb, ob);
  mfma_dense<true, true><<<dim3(8, 32), 256, 0, stream>>>(ob, proj_w, proj_b, x, x2, 1024, 1024);
  rms_kernel<true><<<4096, 256, 0, stream>>>(x2, ln2_w, xn2, xn2b);
  hipMemsetAsync(probsum, 0, 8 * sizeof(float), stream);
  router_kernel<<<1024, 256, 0, stream>>>(xn2, route_w, route_b, noise_w, noise_b, noise_eps,
                                          topi, flat_p, probsum, slotmap);
  scan_kernel<<<1, 512, 0, stream>>>(topi, flat_p, tok, gateb, cntb, slotmap);
  mfma_swiglu<<<dim3(43, 8, 8), 256, 0, stream>>>(xn2b, swiglu_w, tok, cntb, ACT);
  mfma_down<<<dim3(8, 8, 8), 256, 0, stream>>>(ACT, down_w, OE);
  combine_kernel<<<4096, 256, 0, stream>>>(x2, OE, topi, slotmap, flat_p, out);
  aux_kernel<<<1, 64, 0, stream>>>(probsum, out);
}

// Round 4
// 1166.000 us; speedup vs baseline: 2.6860x; 1.1816x over previous
//
#include <hip/hip_runtime.h>
#include <math.h>

#define NTOK   4096
#define DM     1024
#define NHEAD  16
#define HDIM   64
#define NEXP   8
#define CAP    1024
#define HID    2730
#define NFF2   5460
#define HIDP   2752   // HID padded to multiple of 32

typedef __attribute__((ext_vector_type(8))) short bf16x8;
typedef __attribute__((ext_vector_type(4))) float f32x4;
typedef __attribute__((ext_vector_type(8))) _Float16 h16x8;
typedef __attribute__((ext_vector_type(4))) _Float16 h16x4;
typedef __attribute__((ext_vector_type(8))) unsigned short u16x8;

__device__ __forceinline__ unsigned short f2bf(float f) {
  unsigned int u = __float_as_uint(f);
  u += 0x7fffu + ((u >> 16) & 1u);
  return (unsigned short)(u >> 16);
}

// ============================ pack weights ============================
__global__ void pack_kernel(const float* __restrict__ q_w, const float* __restrict__ ka_w,
                            const float* __restrict__ va_w, float* __restrict__ Wq,
                            float* __restrict__ Wlat) {
  int idx = blockIdx.x * 256 + threadIdx.x;
  if (idx < 1048576) {
    int d = idx >> 10, nn = idx & 1023;
    int h = nn >> 6, e = nn & 63;
    Wq[idx] = q_w[((size_t)h * 1024 + d) * 64 + e];
  } else {
    int j = idx - 1048576;
    int d = j >> 10, nn = j & 1023;
    if (nn < 512) {
      int h = nn >> 5, l = nn & 31;
      Wlat[j] = ka_w[((size_t)h * 1024 + d) * 32 + l];
    } else {
      int c = nn - 512;
      int h = c >> 5, l = c & 31;
      Wlat[j] = va_w[((size_t)h * 1024 + d) * 32 + l];
    }
  }
}

// ============================ RMSNorm ============================
template <bool DUAL>
__global__ __launch_bounds__(256) void rms_kernel(const float* __restrict__ x,
                                                  const float* __restrict__ w,
                                                  float* __restrict__ out,
                                                  unsigned short* __restrict__ outb) {
  int row = blockIdx.x;
  int tid = threadIdx.x;
  const float4 v = ((const float4*)(x + (size_t)row * DM))[tid];
  float ss = v.x * v.x + v.y * v.y + v.z * v.z + v.w * v.w;
#pragma unroll
  for (int off = 32; off >= 1; off >>= 1) ss += __shfl_down(ss, off);
  __shared__ float red[4];
  if ((tid & 63) == 0) red[tid >> 6] = ss;
  __syncthreads();
  float tot = red[0] + red[1] + red[2] + red[3];
  float scale = rsqrtf(tot * (1.0f / 1024.0f) + 1e-5f);
  const float4 wv = ((const float4*)w)[tid];
  float4 o;
  o.x = v.x * scale * wv.x; o.y = v.y * scale * wv.y;
  o.z = v.z * scale * wv.z; o.w = v.w * scale * wv.w;
  ((float4*)(out + (size_t)row * DM))[tid] = o;
  if (DUAL) {
    ushort4 ob;
    ob.x = f2bf(o.x); ob.y = f2bf(o.y); ob.z = f2bf(o.z); ob.w = f2bf(o.w);
    *(ushort4*)(outb + (size_t)row * DM + tid * 4) = ob;
  }
}

// ============================ dense bf16 MFMA GEMM ============================
// C[M,N] = A[M,K]@B[K,N] (+bias)(+res). grid.x = M-tiles (for weight-slab L2 reuse).
template <bool BIAS, bool RES>
__global__ __launch_bounds__(256) void mfma_dense(const float* __restrict__ A,
                                                  const float* __restrict__ Bm,
                                                  const float* __restrict__ bias,
                                                  const float* __restrict__ res,
                                                  float* __restrict__ C, int K, int N) {
  int m0 = blockIdx.x * 128;
  int n0 = blockIdx.y * 128;
  __shared__ short As[128][40];
  __shared__ short Bs[128][40];
  int tid = threadIdx.x;
  int wid = tid >> 6, lane = tid & 63;
  int wm0 = (wid >> 1) * 64, wn0 = (wid & 1) * 64;
  int lr = lane & 15, lq = lane >> 4;
  f32x4 c[4][4];
  f32x4 zz = {0.f, 0.f, 0.f, 0.f};
#pragma unroll
  for (int i = 0; i < 4; i++)
#pragma unroll
    for (int j = 0; j < 4; j++) c[i][j] = zz;
  int ar = tid >> 2;
  int aq = tid & 3;
  int bn = tid & 127;          // B: output col within tile
  int bh = tid >> 7;           // B: k-half (0/1)
  const float* Bp = Bm + n0 + bn;
  for (int kc = 0; kc < K; kc += 32) {
    __syncthreads();
#pragma unroll
    for (int rr = 0; rr < 2; rr++) {
      int row = rr * 64 + ar;
      const float* ap = A + (size_t)(m0 + row) * K + kc + aq * 8;
      float4 a0 = *(const float4*)ap;
      float4 a1 = *(const float4*)(ap + 4);
      u16x8 pk;
      pk[0] = f2bf(a0.x); pk[1] = f2bf(a0.y); pk[2] = f2bf(a0.z); pk[3] = f2bf(a0.w);
      pk[4] = f2bf(a1.x); pk[5] = f2bf(a1.y); pk[6] = f2bf(a1.z); pk[7] = f2bf(a1.w);
      *(u16x8*)&As[row][aq * 8] = pk;
    }
    // B: thread reads 16 k-strided floats at fixed col (coalesced across lanes),
    // writes two b128s — conflict-free (40-short stride: 8 lanes cover 32 banks).
    {
      const float* bp = Bp + (size_t)(kc + bh * 16) * N;
      u16x8 p0, p1;
#pragma unroll
      for (int j = 0; j < 8; j++) p0[j] = f2bf(bp[(size_t)j * N]);
#pragma unroll
      for (int j = 0; j < 8; j++) p1[j] = f2bf(bp[(size_t)(j + 8) * N]);
      *(u16x8*)&Bs[bn][bh * 16] = p0;
      *(u16x8*)&Bs[bn][bh * 16 + 8] = p1;
    }
    __syncthreads();
    bf16x8 a[4], b[4];
#pragma unroll
    for (int mi = 0; mi < 4; mi++) a[mi] = *(bf16x8*)&As[wm0 + mi * 16 + lr][lq * 8];
#pragma unroll
    for (int ni = 0; ni < 4; ni++) b[ni] = *(bf16x8*)&Bs[wn0 + ni * 16 + lr][lq * 8];
#pragma unroll
    for (int mi = 0; mi < 4; mi++)
#pragma unroll
      for (int ni = 0; ni < 4; ni++)
        c[mi][ni] = __builtin_amdgcn_mfma_f32_16x16x32_bf16(a[mi], b[ni], c[mi][ni], 0, 0, 0);
  }
#pragma unroll
  for (int mi = 0; mi < 4; mi++)
#pragma unroll
    for (int ni = 0; ni < 4; ni++) {
      int nn = n0 + wn0 + ni * 16 + lr;
      float bv = BIAS ? bias[nn] : 0.f;
#pragma unroll
      for (int r = 0; r < 4; r++) {
        int mm = m0 + wm0 + mi * 16 + lq * 4 + r;
        float v = c[mi][ni][r] + bv;
        if (RES) v += res[(size_t)mm * N + nn];
        C[(size_t)mm * N + nn] = v;
      }
    }
}

// ============================ latent -> K,V expand (V out f16) ============================
__global__ void expand_kernel(const float* __restrict__ latents, const float* __restrict__ kb_w,
                              const float* __restrict__ vb_w, float* __restrict__ kpre,
                              _Float16* __restrict__ vf) {
  int idx = blockIdx.x * 256 + threadIdx.x;  // 4M
  int e = idx & 63;
  int t = (idx >> 6) & 1023;
  int h = (idx >> 16) & 15;
  int b = idx >> 20;
  const float* lrow = latents + ((size_t)(b * 1024 + t)) * DM;
  const float* kb = kb_w + (size_t)h * 2048;
  const float* vb = vb_w + (size_t)h * 2048;
  float ka = 0.f, va = 0.f;
#pragma unroll
  for (int l = 0; l < 32; l++) {
    ka += lrow[h * 32 + l] * kb[l * 64 + e];
    va += lrow[512 + h * 32 + l] * vb[l * 64 + e];
  }
  kpre[idx] = ka;
  vf[idx] = (_Float16)va;
}

// ============================ RoPE (out f16) ============================
template <bool IN_BTHD>
__global__ void rope_kernel(const float* __restrict__ in, _Float16* __restrict__ out) {
  int idx = blockIdx.x * 256 + threadIdx.x;  // 2M
  int i = idx & 31;
  int t = (idx >> 5) & 1023;
  int h = (idx >> 15) & 15;
  int b = idx >> 19;
  size_t ib;
  if (IN_BTHD)
    ib = ((size_t)(b * 1024 + t)) * DM + h * 64;
  else
    ib = ((size_t)((b * 16 + h) * 1024 + t)) * 64;
  float t1 = in[ib + 2 * i], t2 = in[ib + 2 * i + 1];
  float inv = exp2f(-(float)i * 0.41524101186091903f);  // 10000^(-i/32)
  float ang = (float)t * inv;
  float s, c;
  sincosf(ang, &s, &c);
  size_t ob = ((size_t)((b * 16 + h) * 1024 + t)) * 64;
  out[ob + i] = (_Float16)(t1 * c - t2 * s);
  out[ob + 32 + i] = (_Float16)(t1 * s + t2 * c);
}

// ============================ flash attention (f16 MFMA) ============================
__global__ __launch_bounds__(256) void attn_mfma(const _Float16* __restrict__ qf,
                                                 const _Float16* __restrict__ kf,
                                                 const _Float16* __restrict__ vf,
                                                 float* __restrict__ o) {
  __shared__ _Float16 Ks[64][72];
  __shared__ _Float16 Vt[64][68];
  int bh = blockIdx.y;
  int q0 = blockIdx.x * 64;
  int tid = threadIdx.x;
  int wv = tid >> 6, lane = tid & 63;
  int lr = lane & 15, lq = lane >> 4;
  const size_t base = (size_t)bh * 1024 * 64;
  const _Float16* qrow = qf + base + (size_t)(q0 + wv * 16 + lr) * 64;
  h16x8 qfr[2];
  qfr[0] = *(const h16x8*)(qrow + lq * 8);
  qfr[1] = *(const h16x8*)(qrow + 32 + lq * 8);
  float mrow = -3.0e38f, lsum = 0.f;
  f32x4 oacc[4];
  f32x4 zz = {0.f, 0.f, 0.f, 0.f};
#pragma unroll
  for (int i = 0; i < 4; i++) oacc[i] = zz;
  int skey = tid >> 2, spart = tid & 3;
  int vkey = tid & 63, vdb = (tid >> 6) * 16;

  for (int kt = 0; kt < 16; kt++) {
    __syncthreads();
    {
      const _Float16* kg = kf + base + (size_t)(kt * 64 + skey) * 64 + spart * 16;
      *(h16x8*)&Ks[skey][spart * 16] = *(const h16x8*)kg;
      *(h16x8*)&Ks[skey][spart * 16 + 8] = *(const h16x8*)(kg + 8);
      const _Float16* vg = vf + base + (size_t)(kt * 64 + vkey) * 64 + vdb;
      h16x8 v0 = *(const h16x8*)vg;
      h16x8 v1 = *(const h16x8*)(vg + 8);
#pragma unroll
      for (int j = 0; j < 8; j++) {
        Vt[vdb + j][vkey] = v0[j];
        Vt[vdb + 8 + j][vkey] = v1[j];
      }
    }
    __syncthreads();
    f32x4 st[4];
#pragma unroll
    for (int ni = 0; ni < 4; ni++) {
      st[ni] = zz;
#pragma unroll
      for (int kc = 0; kc < 2; kc++) {
        h16x8 ak = *(const h16x8*)&Ks[ni * 16 + lr][kc * 32 + lq * 8];
        st[ni] = __builtin_amdgcn_mfma_f32_16x16x32_f16(ak, qfr[kc], st[ni], 0, 0, 0);
      }
    }
    float smax = -3.0e38f;
#pragma unroll
    for (int ni = 0; ni < 4; ni++)
#pragma unroll
      for (int r = 0; r < 4; r++) {
        st[ni][r] *= 0.125f;
        smax = fmaxf(smax, st[ni][r]);
      }
    smax = fmaxf(smax, __shfl_xor(smax, 16));
    smax = fmaxf(smax, __shfl_xor(smax, 32));
    float newm = fmaxf(mrow, smax);
    float alpha = expf(mrow - newm);
    float rsum = 0.f;
    h16x4 pf[4];
#pragma unroll
    for (int ni = 0; ni < 4; ni++)
#pragma unroll
      for (int r = 0; r < 4; r++) {
        float p = expf(st[ni][r] - newm);
        rsum += p;
        pf[ni][r] = (_Float16)p;
      }
    rsum += __shfl_xor(rsum, 16);
    rsum += __shfl_xor(rsum, 32);
    lsum = lsum * alpha + rsum;
    mrow = newm;
#pragma unroll
    for (int dt = 0; dt < 4; dt++) {
      oacc[dt][0] *= alpha; oacc[dt][1] *= alpha;
      oacc[dt][2] *= alpha; oacc[dt][3] *= alpha;
    }
#pragma unroll
    for (int dt = 0; dt < 4; dt++)
#pragma unroll
      for (int ni = 0; ni < 4; ni++) {
        h16x4 va = *(const h16x4*)&Vt[dt * 16 + lr][ni * 16 + lq * 4];
        oacc[dt] = __builtin_amdgcn_mfma_f32_16x16x16f16(va, pf[ni], oacc[dt], 0, 0, 0);
      }
  }
  int b = bh >> 4, h = bh & 15;
  int qg = q0 + wv * 16 + lr;
  float invl = 1.0f / lsum;
  float* orow = o + (size_t)(b * 1024 + qg) * DM + h * 64;
#pragma unroll
  for (int dt = 0; dt < 4; dt++)
#pragma unroll
    for (int r = 0; r < 4; r++) orow[dt * 16 + lq * 4 + r] = oacc[dt][r] * invl;
}

// ============================ router ============================
__global__ __launch_bounds__(256) void router_kernel(
    const float* __restrict__ xn2, const float* __restrict__ route_w,
    const float* __restrict__ route_b, const float* __restrict__ noise_w,
    const float* __restrict__ noise_b, const float* __restrict__ noise_eps,
    int* __restrict__ topi, float* __restrict__ flat_p, float* __restrict__ probsum,
    int* __restrict__ slotmap) {
  int wave = threadIdx.x >> 6;
  int lane = threadIdx.x & 63;
  int tk = blockIdx.x * 4 + wave;
  float acc[8] = {0.f}, nacc[8] = {0.f};
  const float* xr = xn2 + (size_t)tk * DM;
  for (int it = 0; it < 16; it++) {
    int d = it * 64 + lane;
    float xv = xr[d];
    const float* rw = route_w + d * 8;
    const float* nw = noise_w + d * 8;
#pragma unroll
    for (int e = 0; e < 8; e++) {
      acc[e] += xv * rw[e];
      nacc[e] += xv * nw[e];
    }
  }
#pragma unroll
  for (int off = 32; off >= 1; off >>= 1) {
#pragma unroll
    for (int e = 0; e < 8; e++) {
      acc[e] += __shfl_down(acc[e], off);
      nacc[e] += __shfl_down(nacc[e], off);
    }
  }
  if (lane == 0) {
    float noisy[8];
#pragma unroll
    for (int e = 0; e < 8; e++) {
      float lg = acc[e] + route_b[e];
      float nl = nacc[e] + noise_b[e];
      float sp = (nl > 20.f) ? nl : log1pf(expf(nl));
      noisy[e] = lg + noise_eps[tk * 8 + e] * sp;
    }
    int i1 = 0;
    float n1 = noisy[0];
#pragma unroll
    for (int e = 1; e < 8; e++)
      if (noisy[e] > n1) { n1 = noisy[e]; i1 = e; }
    int i2 = -1;
    float n2 = -3.0e38f;
#pragma unroll
    for (int e = 0; e < 8; e++)
      if (e != i1 && noisy[e] > n2) { n2 = noisy[e]; i2 = e; }
    float r = expf(n2 - n1);
    float p1 = 1.0f / (1.0f + r);
    float p2 = r / (1.0f + r);
    topi[tk * 2] = i1;
    topi[tk * 2 + 1] = i2;
#pragma unroll
    for (int e = 0; e < 8; e++) flat_p[tk * 8 + e] = (e == i1) ? p1 : ((e == i2) ? p2 : 0.f);
    atomicAdd(&probsum[i1], p1);
    atomicAdd(&probsum[i2], p2);
    slotmap[tk * 2] = -1;
    slotmap[tk * 2 + 1] = -1;
  }
}

// ============================ capacity scan ============================
__global__ __launch_bounds__(512) void scan_kernel(const int* __restrict__ topi,
                                                   const float* __restrict__ flat_p,
                                                   int* __restrict__ tok, float* __restrict__ gate,
                                                   int* __restrict__ cnt, int* __restrict__ slotmap) {
  int e = threadIdx.x >> 6;
  int lane = threadIdx.x & 63;
  int count = 0;
  for (int base = 0; base < NTOK; base += 64) {
    int t = base + lane;
    int a = topi[t * 2], b = topi[t * 2 + 1];
    bool mflag = (a == e) || (b == e);
    unsigned long long mask = __ballot(mflag);
    int pos = count + __popcll(mask & ((1ull << lane) - 1ull));
    if (mflag && pos < CAP) {
      tok[e * CAP + pos] = t;
      gate[e * CAP + pos] = flat_p[t * 8 + e];
      int k = (a == e) ? 0 : 1;
      slotmap[t * 2 + k] = pos;
    }
    count += __popcll(mask);
  }
  if (lane == 0) cnt[e] = (count < CAP) ? count : CAP;
}

// ============================ expert GEMM 1 (bf16 MFMA): gathered x @ swiglu_w, fused SiLU ======
// grid (8 m-tiles, 43 j-tiles, 8 experts) — m fastest for weight-slab L2 reuse.
__global__ __launch_bounds__(256) void mfma_swiglu(const unsigned short* __restrict__ xn2b,
                                                   const float* __restrict__ swiglu_w,
                                                   const int* __restrict__ tok,
                                                   const int* __restrict__ cnt,
                                                   unsigned short* __restrict__ ACT) {
  int e = blockIdx.z;
  int m0 = blockIdx.x * 128;
  int j0 = blockIdx.y * 64;
  __shared__ short As[128][40];
  __shared__ short B1s[64][40];
  __shared__ short B2s[64][40];
  __shared__ int tokL[128];
  int tid = threadIdx.x;
  if (tid < 128) {
    int slot = m0 + tid;
    tokL[tid] = (slot < cnt[e]) ? tok[e * CAP + slot] : -1;
  }
  __syncthreads();
  int wid = tid >> 6, lane = tid & 63;
  int wm0 = (wid >> 1) * 64, wn0 = (wid & 1) * 32;
  int lr = lane & 15, lq = lane >> 4;
  f32x4 c1[4][2], c2[4][2];
  f32x4 zz = {0.f, 0.f, 0.f, 0.f};
#pragma unroll
  for (int i = 0; i < 4; i++)
#pragma unroll
    for (int j = 0; j < 2; j++) { c1[i][j] = zz; c2[i][j] = zz; }
  const float* Wb = swiglu_w + (size_t)e * DM * NFF2;
  int ar = tid >> 2;
  int aq = tid & 3;
  int tr0 = tokL[ar], tr1 = tokL[64 + ar];
  // B staging coords: fixed col per thread, 8 k-strided loads, one b128 write per half
  int bnn = tid & 63;          // col within j-tile
  int bkq = tid >> 6;          // k-octet (0..3)
  int col = j0 + bnn;
  bool cvalid = col < HID;
  const float* Wc1 = Wb + col;
  const float* Wc2 = Wb + HID + col;

  for (int kc = 0; kc < DM; kc += 32) {
    __syncthreads();
    {
      float4 av = {0.f, 0.f, 0.f, 0.f};
      if (tr0 >= 0) av = *(const float4*)(xn2b + (size_t)tr0 * DM + kc + aq * 8);
      *(float4*)&As[ar][aq * 8] = av;
      float4 av2 = {0.f, 0.f, 0.f, 0.f};
      if (tr1 >= 0) av2 = *(const float4*)(xn2b + (size_t)tr1 * DM + kc + aq * 8);
      *(float4*)&As[64 + ar][aq * 8] = av2;
    }
    {
      const float* p1 = Wc1 + (size_t)(kc + bkq * 8) * NFF2;
      const float* p2 = Wc2 + (size_t)(kc + bkq * 8) * NFF2;
      u16x8 k1, k2;
#pragma unroll
      for (int j = 0; j < 8; j++) {
        float v1 = cvalid ? p1[(size_t)j * NFF2] : 0.f;
        float v2 = cvalid ? p2[(size_t)j * NFF2] : 0.f;
        k1[j] = f2bf(v1);
        k2[j] = f2bf(v2);
      }
      *(u16x8*)&B1s[bnn][bkq * 8] = k1;
      *(u16x8*)&B2s[bnn][bkq * 8] = k2;
    }
    __syncthreads();
    bf16x8 a[4], b1[2], b2[2];
#pragma unroll
    for (int mi = 0; mi < 4; mi++) a[mi] = *(bf16x8*)&As[wm0 + mi * 16 + lr][lq * 8];
#pragma unroll
    for (int ni = 0; ni < 2; ni++) {
      b1[ni] = *(bf16x8*)&B1s[wn0 + ni * 16 + lr][lq * 8];
      b2[ni] = *(bf16x8*)&B2s[wn0 + ni * 16 + lr][lq * 8];
    }
#pragma unroll
    for (int mi = 0; mi < 4; mi++)
#pragma unroll
      for (int ni = 0; ni < 2; ni++) {
        c1[mi][ni] = __builtin_amdgcn_mfma_f32_16x16x32_bf16(a[mi], b1[ni], c1[mi][ni], 0, 0, 0);
        c2[mi][ni] = __builtin_amdgcn_mfma_f32_16x16x32_bf16(a[mi], b2[ni], c2[mi][ni], 0, 0, 0);
      }
  }
#pragma unroll
  for (int mi = 0; mi < 4; mi++)
#pragma unroll
    for (int ni = 0; ni < 2; ni++)
#pragma unroll
      for (int r = 0; r < 4; r++) {
        int mm = m0 + wm0 + mi * 16 + lq * 4 + r;
        int cc = j0 + wn0 + ni * 16 + lr;
        float h1 = c1[mi][ni][r], h2 = c2[mi][ni][r];
        float act = (h1 / (1.0f + expf(-h1))) * h2;
        ACT[(size_t)e * CAP * HIDP + (size_t)mm * HIDP + cc] = f2bf(act);
      }
}

// ============================ expert GEMM 2 (bf16 MFMA): ACT @ down_w -> OE fp32 ============
// grid (8 m, 8 n, 8 e) — m fastest for weight-slab L2 reuse.
__global__ __launch_bounds__(256) void mfma_down(const unsigned short* __restrict__ ACT,
                                                 const float* __restrict__ down_w,
                                                 float* __restrict__ OE) {
  int e = blockIdx.z;
  int m0 = blockIdx.x * 128;
  int n0 = blockIdx.y * 128;
  __shared__ short As[128][40];
  __shared__ short Bs[128][40];
  int tid = threadIdx.x;
  int wid = tid >> 6, lane = tid & 63;
  int wm0 = (wid >> 1) * 64, wn0 = (wid & 1) * 64;
  int lr = lane & 15, lq = lane >> 4;
  f32x4 c[4][4];
  f32x4 zz = {0.f, 0.f, 0.f, 0.f};
#pragma unroll
  for (int i = 0; i < 4; i++)
#pragma unroll
    for (int j = 0; j < 4; j++) c[i][j] = zz;
  const unsigned short* Ab = ACT + (size_t)e * CAP * HIDP + (size_t)m0 * HIDP;
  const float* Bb = down_w + (size_t)e * HID * DM + n0;
  int ar = tid >> 2;
  int aq = tid & 3;
  int bnn = tid & 127;   // col within n-tile
  int bh = tid >> 7;     // k-half (0/1)
  const float* Bp = Bb + bnn;

  for (int kc = 0; kc < HIDP; kc += 32) {
    __syncthreads();
    *(float4*)&As[ar][aq * 8] = *(const float4*)(Ab + (size_t)ar * HIDP + kc + aq * 8);
    *(float4*)&As[64 + ar][aq * 8] = *(const float4*)(Ab + (size_t)(64 + ar) * HIDP + kc + aq * 8);
    {
      int kb = kc + bh * 16;
      u16x8 p0, p1;
#pragma unroll
      for (int j = 0; j < 8; j++) {
        float v = (kb + j < HID) ? Bp[(size_t)(kb + j) * DM] : 0.f;
        p0[j] = f2bf(v);
      }
#pragma unroll
      for (int j = 0; j < 8; j++) {
        float v = (kb + 8 + j < HID) ? Bp[(size_t)(kb + 8 + j) * DM] : 0.f;
        p1[j] = f2bf(v);
      }
      *(u16x8*)&Bs[bnn][bh * 16] = p0;
      *(u16x8*)&Bs[bnn][bh * 16 + 8] = p1;
    }
    __syncthreads();
    bf16x8 a[4], b[4];
#pragma unroll
    for (int mi = 0; mi < 4; mi++) a[mi] = *(bf16x8*)&As[wm0 + mi * 16 + lr][lq * 8];
#pragma unroll
    for (int ni = 0; ni < 4; ni++) b[ni] = *(bf16x8*)&Bs[wn0 + ni * 16 + lr][lq * 8];
#pragma unroll
    for (int mi = 0; mi < 4; mi++)
#pragma unroll
      for (int ni = 0; ni < 4; ni++)
        c[mi][ni] = __builtin_amdgcn_mfma_f32_16x16x32_bf16(a[mi], b[ni], c[mi][ni], 0, 0, 0);
  }
#pragma unroll
  for (int mi = 0; mi < 4; mi++)
#pragma unroll
    for (int ni = 0; ni < 4; ni++)
#pragma unroll
      for (int r = 0; r < 4; r++) {
        int mm = m0 + wm0 + mi * 16 + lq * 4 + r;
        int nn = n0 + wn0 + ni * 16 + lr;
        OE[((size_t)e << 20) + (size_t)mm * DM + nn] = c[mi][ni][r];
      }
}

// ============================ combine ============================
__global__ void combine_kernel(const float* __restrict__ x2, const float* __restrict__ OE,
                               const int* __restrict__ topi, const int* __restrict__ slotmap,
                               const float* __restrict__ flat_p, float* __restrict__ out) {
  int idx = blockIdx.x * 256 + threadIdx.x;  // 1M float4s
  int t = idx >> 8;
  int c4 = (idx & 255) * 4;
  float4 v = *(const float4*)(x2 + (size_t)t * DM + c4);
#pragma unroll
  for (int k = 0; k < 2; k++) {
    int s = slotmap[t * 2 + k];
    if (s >= 0) {
      int e = topi[t * 2 + k];
      float g = flat_p[t * 8 + e];
      float4 ov = *(const float4*)(OE + ((size_t)e << 20) + (size_t)s * DM + c4);
      v.x += g * ov.x; v.y += g * ov.y; v.z += g * ov.z; v.w += g * ov.w;
    }
  }
  *(float4*)(out + (size_t)t * DM + c4) = v;
}

__global__ void aux_kernel(const float* __restrict__ probsum, float* __restrict__ out) {
  if (threadIdx.x == 0) {
    float s = 0.f;
#pragma unroll
    for (int e = 0; e < 8; e++) {
      float d = probsum[e] * (1.0f / 4096.0f) - 0.125f;
      s += d * d;
    }
    out[4194304] = s;
  }
}

// ============================ launch ============================
extern "C" void kernel_launch(void* const* d_in, const int* in_sizes, int n_in, void* d_out,
                              int out_size, void* d_ws, size_t ws_size, hipStream_t stream) {
  const float* x = (const float*)d_in[0];
  const float* noise_eps = (const float*)d_in[1];
  const float* ln1_w = (const float*)d_in[2];
  const float* ln2_w = (const float*)d_in[3];
  const float* q_w = (const float*)d_in[4];
  const float* q_b = (const float*)d_in[5];
  const float* ka_w = (const float*)d_in[6];
  const float* kb_w = (const float*)d_in[7];
  const float* va_w = (const float*)d_in[8];
  const float* vb_w = (const float*)d_in[9];
  const float* proj_w = (const float*)d_in[10];
  const float* proj_b = (const float*)d_in[11];
  const float* route_w = (const float*)d_in[12];
  const float* route_b = (const float*)d_in[13];
  const float* noise_w = (const float*)d_in[14];
  const float* noise_b = (const float*)d_in[15];
  const float* swiglu_w = (const float*)d_in[16];
  const float* down_w = (const float*)d_in[17];
  float* out = (float*)d_out;
  char* w = (char*)d_ws;
  const size_t MB = 1ull << 20;
  float* xn = (float*)(w + 0 * MB);
  float* qtmp = (float*)(w + 16 * MB);
  float* latents = (float*)(w + 32 * MB);
  float* kpre = (float*)(w + 48 * MB);
  _Float16* qfb = (_Float16*)(w + 64 * MB);   // 8 MB
  _Float16* kfb = (_Float16*)(w + 72 * MB);   // 8 MB
  _Float16* vfb = (_Float16*)(w + 80 * MB);   // 8 MB
  float* ob = (float*)(w + 88 * MB);          // 16 MB -> ends 104
  unsigned short* ACT = (unsigned short*)(w + 0 * MB);  // bf16 43 MB (xn/qtmp/latents dead)
  float* OE = (float*)(w + 48 * MB);                    // 32 MB (kpre/qkv-f16 dead)
  float* x2 = (float*)(w + 128 * MB);
  float* xn2 = (float*)(w + 144 * MB);
  float* Wq = (float*)(w + 160 * MB);
  float* Wlat = (float*)(w + 164 * MB);
  unsigned short* xn2b = (unsigned short*)(w + 160 * MB);  // bf16 8 MB, after Wq/Wlat dead
  char* sm = w + 168 * MB;
  int* topi = (int*)sm;
  int* tok = (int*)(sm + 64 * 1024);
  int* cntb = (int*)(sm + 128 * 1024);
  int* slotmap = (int*)(sm + 192 * 1024);
  float* flat_p = (float*)(sm + 256 * 1024);
  float* gateb = (float*)(sm + 512 * 1024);
  float* probsum = (float*)(sm + 576 * 1024);

  pack_kernel<<<8192, 256, 0, stream>>>(q_w, ka_w, va_w, Wq, Wlat);
  rms_kernel<false><<<4096, 256, 0, stream>>>(x, ln1_w, xn, nullptr);
  mfma_dense<true, false><<<dim3(32, 8), 256, 0, stream>>>(xn, Wq, q_b, nullptr, qtmp, 1024, 1024);
  mfma_dense<false, false><<<dim3(32, 8), 256, 0, stream>>>(xn, Wlat, nullptr, nullptr, latents, 1024, 1024);
  expand_kernel<<<16384, 256, 0, stream>>>(latents, kb_w, vb_w, kpre, vfb);
  rope_kernel<true><<<8192, 256, 0, stream>>>(qtmp, qfb);
  rope_kernel<false><<<8192, 256, 0, stream>>>(kpre, kfb);
  attn_mfma<<<dim3(16, 64), 256, 0, stream>>>(qfb, kfb, vfb, ob);
  mfma_dense<true, true><<<dim3(32, 8), 256, 0, stream>>>(ob, proj_w, proj_b, x, x2, 1024, 1024);
  rms_kernel<true><<<4096, 256, 0, stream>>>(x2, ln2_w, xn2, xn2b);
  hipMemsetAsync(probsum, 0, 8 * sizeof(float), stream);
  router_kernel<<<1024, 256, 0, stream>>>(xn2, route_w, route_b, noise_w, noise_b, noise_eps,
                                          topi, flat_p, probsum, slotmap);
  scan_kernel<<<1, 512, 0, stream>>>(topi, flat_p, tok, gateb, cntb, slotmap);
  mfma_swiglu<<<dim3(8, 43, 8), 256, 0, stream>>>(xn2b, swiglu_w, tok, cntb, ACT);
  mfma_down<<<dim3(8, 8, 8), 256, 0, stream>>>(ACT, down_w, OE);
  combine_kernel<<<4096, 256, 0, stream>>>(x2, OE, topi, slotmap, flat_p, out);
  aux_kernel<<<1, 64, 0, stream>>>(probsum, out);
}